// Round 9
// baseline (336.370 us; speedup 1.0000x reference)
//
#include <hip/hip_runtime.h>

#define HH 128
#define WW 128
#define CC 64
#define ROW (WW*CC)          // 8192 elements per (b,h) row
#define SLOTB 128            // bytes per px slot in conv LDS (64 f16, linear)
#define ROWB (130*SLOTB)     // 16640 B per staged row (130 slots)
#define FSTR 68              // conv epilogue restage stride (floats) - conflict-free

typedef _Float16 half8 __attribute__((ext_vector_type(8)));
typedef _Float16 half4v __attribute__((ext_vector_type(4)));
typedef float floatx4 __attribute__((ext_vector_type(4)));

__device__ inline floatx4 rcp4(floatx4 v)
{
    floatx4 r;
    r[0] = __builtin_amdgcn_rcpf(v[0]);
    r[1] = __builtin_amdgcn_rcpf(v[1]);
    r[2] = __builtin_amdgcn_rcpf(v[2]);
    r[3] = __builtin_amdgcn_rcpf(v[3]);
    return r;
}

// ---------------------------------------------------------------------------
// Repack HWIO fp32 weights [3][3][64][64] -> f16 B-frag layout:
// W2[(step*4+q)*512 + o*8 + j] = W[tap][kc*32+q*8+j][o], step = tap*2+kc
// ---------------------------------------------------------------------------
__global__ __launch_bounds__(256)
void repack_w(const float* __restrict__ wf, const float* __restrict__ wg,
              _Float16* __restrict__ W2f, _Float16* __restrict__ W2g)
{
    int idx = blockIdx.x * 256 + threadIdx.x;      // 0..73727
    int sel = idx >= 36864;
    int id  = sel ? idx - 36864 : idx;             // (t*64 + c)*64 + o
    const float* src = sel ? wg : wf;
    _Float16* dst = sel ? W2g : W2f;
    int t = id >> 12, c = (id >> 6) & 63, o = id & 63;
    int kc = c >> 5, q = (c >> 3) & 3, j = c & 7;
    int pos = ((((t*2 + kc)*4 + q)*64 + o) << 3) + j;
    dst[pos] = (_Float16)src[id];
}

// ---------------------------------------------------------------------------
// conv1: implicit-GEMM 3x3 SAME conv via f16 MFMA. EXACT R9 form (the best-
// measured 321us config): 256 thr, 2-row blocks, 2 blocks/CU, acc[4][4].
// Writes f16 fbuf + PRE-SWIZZLED y2 = relu(bn_g(acc)) for the fused kernel's
// global_load_lds staging. XOR channel-block swizzle, FSTR=68 restage.
// (R10 ring / R11 512thr / R12 B-preload / R13 1-row all neutral-or-worse —
//  conv-internal knobs exhausted; R14 removes conv2 instead.)
// ---------------------------------------------------------------------------
template<int BNIN, int EPI>
__global__ __launch_bounds__(256, 2)
void conv_mfma(const void* __restrict__ srcv, const _Float16* __restrict__ W2,
               _Float16* __restrict__ outH, float* __restrict__ outF,
               _Float16* __restrict__ y2,
               const float* __restrict__ ig, const float* __restrict__ ib,
               const float* __restrict__ imu, const float* __restrict__ iva,
               const float* __restrict__ og, const float* __restrict__ ob,
               const float* __restrict__ om, const float* __restrict__ ov)
{
    __shared__ __align__(16) char smem[69632];     // max(stage 66560, restage 69632)
    const int t = threadIdx.x;
    const int blk = ((blockIdx.x & 7) << 7) | (blockIdx.x >> 3);  // XCD swizzle
    const int b = blk >> 6, i0 = (blk & 63) * 2;

    const int c8 = (t & 7) << 3;
    float scv[8], biv[8];
    if (BNIN) {
        #pragma unroll
        for (int j = 0; j < 8; ++j) {
            float s = ig[c8+j] * rsqrtf(iva[c8+j] + 1e-3f);
            scv[j] = s; biv[j] = ib[c8+j] - imu[c8+j]*s;
        }
    }

    // zero edge pixel slots (0 and 129) x 4 rows
    {
        int rr = t >> 6, s = (t >> 5) & 1;
        *(float*)(smem + rr*ROWB + (s ? 129*SLOTB : 0) + ((t & 31) << 2)) = 0.f;
    }

    // ---- stage 4 input rows (i0-1 .. i0+2)
    if (BNIN) {
        for (int r = 0; r < 4; ++r) {
            int iy = i0 - 1 + r;
            bool inb = (iy >= 0) && (iy < HH);
            #pragma unroll
            for (int k = 0; k < 4; ++k) {
                int idx = t + (k << 8);
                int px = idx >> 3;
                half8 v = {0,0,0,0,0,0,0,0};
                if (inb) {
                    const float* gp = (const float*)srcv
                        + ((size_t)(b*HH + iy))*ROW + px*CC + c8;
                    float4 u0 = *(const float4*)gp;
                    float4 u1 = *(const float4*)(gp + 4);
                    v[0] = (_Float16)fmaxf(0.f, u0.x*scv[0] + biv[0]);
                    v[1] = (_Float16)fmaxf(0.f, u0.y*scv[1] + biv[1]);
                    v[2] = (_Float16)fmaxf(0.f, u0.z*scv[2] + biv[2]);
                    v[3] = (_Float16)fmaxf(0.f, u0.w*scv[3] + biv[3]);
                    v[4] = (_Float16)fmaxf(0.f, u1.x*scv[4] + biv[4]);
                    v[5] = (_Float16)fmaxf(0.f, u1.y*scv[5] + biv[5]);
                    v[6] = (_Float16)fmaxf(0.f, u1.z*scv[6] + biv[6]);
                    v[7] = (_Float16)fmaxf(0.f, u1.w*scv[7] + biv[7]);
                }
                int key = ((px + 1) & 7) << 4;
                *(half8*)(smem + r*ROWB + (px + 1)*SLOTB
                          + ((((t & 7) << 4)) ^ key)) = v;
            }
        }
    } else {
        const _Float16* src = (const _Float16*)srcv;
        #pragma unroll
        for (int r = 0; r < 4; ++r) {
            int iy = i0 - 1 + r;
            char* lb = smem + r*ROWB + SLOTB;
            if (iy >= 0 && iy < HH) {
                const _Float16* gp = src + (size_t)(b*HH + iy)*ROW;
                #pragma unroll
                for (int k = 0; k < 4; ++k) {
                    int eo = ((k << 8) + t) << 3;
                    __builtin_amdgcn_global_load_lds(
                        (const __attribute__((address_space(1))) void*)(gp + eo),
                        (__attribute__((address_space(3))) void*)(lb + (eo << 1)),
                        16, 0, 0);
                }
            } else {
                half8 z = {0,0,0,0,0,0,0,0};
                #pragma unroll
                for (int k = 0; k < 4; ++k)
                    *(half8*)(lb + (((k << 8) + t) << 4)) = z;
            }
        }
    }
    __syncthreads();

    const int wv = t >> 6, lane = t & 63;
    const int lm = lane & 15, quad = lane >> 4;
    const int r  = wv >> 1;
    const int px0 = (wv & 1) * 64;
    floatx4 z4 = {0.f,0.f,0.f,0.f};
    floatx4 acc[4][4];
    #pragma unroll
    for (int ms = 0; ms < 4; ++ms)
        #pragma unroll
        for (int nt = 0; nt < 4; ++nt) acc[ms][nt] = z4;

    #pragma unroll
    for (int tap = 0; tap < 9; ++tap) {
        const int di = tap / 3, dj = tap % 3;
        const int slot = px0 + lm + dj;
        const int key  = (slot & 7) << 4;
        const char* abase = smem + (r + di)*ROWB + slot*SLOTB;
        #pragma unroll
        for (int kc = 0; kc < 2; ++kc) {
            const char* ab = abase + ((kc*64 + quad*16) ^ key);
            half8 a0 = *(const half8*)(ab);
            half8 a1 = *(const half8*)(ab + 16*SLOTB);
            half8 a2 = *(const half8*)(ab + 32*SLOTB);
            half8 a3 = *(const half8*)(ab + 48*SLOTB);
            const _Float16* wb = W2 + (((tap*2 + kc)*4 + quad) << 9) + (lm << 3);
            half8 b0 = *(const half8*)(wb);
            half8 b1 = *(const half8*)(wb + 128);
            half8 b2 = *(const half8*)(wb + 256);
            half8 b3 = *(const half8*)(wb + 384);
            acc[0][0] = __builtin_amdgcn_mfma_f32_16x16x32_f16(a0, b0, acc[0][0], 0,0,0);
            acc[1][0] = __builtin_amdgcn_mfma_f32_16x16x32_f16(a1, b0, acc[1][0], 0,0,0);
            acc[2][0] = __builtin_amdgcn_mfma_f32_16x16x32_f16(a2, b0, acc[2][0], 0,0,0);
            acc[3][0] = __builtin_amdgcn_mfma_f32_16x16x32_f16(a3, b0, acc[3][0], 0,0,0);
            acc[0][1] = __builtin_amdgcn_mfma_f32_16x16x32_f16(a0, b1, acc[0][1], 0,0,0);
            acc[1][1] = __builtin_amdgcn_mfma_f32_16x16x32_f16(a1, b1, acc[1][1], 0,0,0);
            acc[2][1] = __builtin_amdgcn_mfma_f32_16x16x32_f16(a2, b1, acc[2][1], 0,0,0);
            acc[3][1] = __builtin_amdgcn_mfma_f32_16x16x32_f16(a3, b1, acc[3][1], 0,0,0);
            acc[0][2] = __builtin_amdgcn_mfma_f32_16x16x32_f16(a0, b2, acc[0][2], 0,0,0);
            acc[1][2] = __builtin_amdgcn_mfma_f32_16x16x32_f16(a1, b2, acc[1][2], 0,0,0);
            acc[2][2] = __builtin_amdgcn_mfma_f32_16x16x32_f16(a2, b2, acc[2][2], 0,0,0);
            acc[3][2] = __builtin_amdgcn_mfma_f32_16x16x32_f16(a3, b2, acc[3][2], 0,0,0);
            acc[0][3] = __builtin_amdgcn_mfma_f32_16x16x32_f16(a0, b3, acc[0][3], 0,0,0);
            acc[1][3] = __builtin_amdgcn_mfma_f32_16x16x32_f16(a1, b3, acc[1][3], 0,0,0);
            acc[2][3] = __builtin_amdgcn_mfma_f32_16x16x32_f16(a2, b3, acc[2][3], 0,0,0);
            acc[3][3] = __builtin_amdgcn_mfma_f32_16x16x32_f16(a3, b3, acc[3][3], 0,0,0);
        }
    }

    // ---- epilogue: restage fp32 acc -> LDS [256 px][FSTR], vector copy-out
    __syncthreads();
    float* sF = (float*)smem;
    #pragma unroll
    for (int nt = 0; nt < 4; ++nt) {
        int c = nt*16 + lm;
        #pragma unroll
        for (int ms = 0; ms < 4; ++ms) {
            int pix = r*128 + px0 + ms*16 + quad*4;
            floatx4 v = acc[ms][nt];
            #pragma unroll
            for (int rv = 0; rv < 4; ++rv)
                sF[(pix + rv)*FSTR + c] = v[rv];
        }
    }
    __syncthreads();

    const size_t gbase = ((size_t)(b*HH + i0)) * ROW;
    if (EPI) {
        const int c8o = (t & 7) << 3;
        float s8[8], bb8[8];
        #pragma unroll
        for (int j = 0; j < 8; ++j) {
            float ss = og[c8o+j] * rsqrtf(ov[c8o+j] + 1e-3f);
            s8[j] = ss; bb8[j] = ob[c8o+j] - om[c8o+j]*ss;
        }
        #pragma unroll
        for (int jj = 0; jj < 8; ++jj) {
            int chunk = jj*256 + t;
            int px = chunk >> 3;
            const float* sp = sF + px*FSTR + c8o;
            floatx4 u0 = *(const floatx4*)(sp);
            floatx4 u1 = *(const floatx4*)(sp + 4);
            half8 hv, yv;
            #pragma unroll
            for (int j = 0; j < 4; ++j) {
                hv[j]   = (_Float16)u0[j];
                hv[4+j] = (_Float16)u1[j];
                yv[j]   = (_Float16)fmaxf(0.f, u0[j]*s8[j]   + bb8[j]);
                yv[4+j] = (_Float16)fmaxf(0.f, u1[j]*s8[4+j] + bb8[4+j]);
            }
            size_t oe = gbase + (size_t)px*64 + c8o;
            *(half8*)(outH + oe) = hv;
            int pxr = px & 127;
            int key8 = ((pxr + 1) & 7) << 3;
            *(half8*)(y2 + gbase + (size_t)px*64 + (c8o ^ key8)) = yv;
        }
    } else {
        #pragma unroll
        for (int jj = 0; jj < 8; ++jj) {
            int chunk = jj*256 + t;
            int px = chunk >> 3;
            const int cc = (t & 7) << 3;
            const float* sp = sF + px*FSTR + cc;
            size_t oe = gbase + (size_t)px*64 + cc;
            *(floatx4*)(outF + oe)     = *(const floatx4*)(sp);
            *(floatx4*)(outF + oe + 4) = *(const floatx4*)(sp + 4);
        }
    }
}

// ---------------------------------------------------------------------------
// R14 FUSED: conv2 + Sobel + K=5 diffusion + relu(bn_o). One block per (b,h)
// row, 1024 thr, 1 block/CU (LDS 115456 B), 16 waves/CU.
// Phases:
//  1. DMA pre-swizzled y2 rows i-1,i,i+1 -> S (proven conv2 staging; zero-fill
//     OOB = conv2 'SAME' zero-pad); fp32 f[im]->B0, f[ip]->B1 (reflect, Sobel).
//  2. Sobel partials (B0,B1) + conv2 MFMA from S (16 waves: wave = 16px x
//     32cout, acc x2; R12-proven ch-split B-frags). Both read-only.
//  3. B0 <- f[i] (prefetched regs); B1 <- g (acc restage, same [w][64] layout
//     the old code staged the g GLOBAL LOAD into - coef phase unchanged).
//  4. coef phase (proven) + g stored to out1 from the gv regs it already has.
//  5. K=5 diffusion ping-pong B0/B1 + bn_o epilogue (proven, unchanged).
// Numerics: y2 produced by conv1 and consumed identically to the old conv2
// kernel -> bit-identical g and h. Eliminates the entire conv2 dispatch and
// its 64 MB g read-back.
// ---------------------------------------------------------------------------
__global__ __launch_bounds__(1024, 4)
void diffuse_fused(const _Float16* __restrict__ f, const _Float16* __restrict__ y2,
                   const _Float16* __restrict__ W2g,
                   float* __restrict__ gout, float* __restrict__ out,
                   const float* __restrict__ bog, const float* __restrict__ bob,
                   const float* __restrict__ bom, const float* __restrict__ bov)
{
    __shared__ __align__(16) char S[3*ROWB];       // 49920 B y2 slot-stage
    __shared__ float B0[ROW], B1[ROW];             // 2 x 32 KB
    const int t = threadIdx.x;
    const int rowb = ((blockIdx.x & 7) << 8) | (blockIdx.x >> 3);  // XCD swizzle
    const int b = rowb >> 7, i = rowb & 127;
    const int im = (i == 0)    ? 1    : i - 1;     // reflect (Sobel)
    const int ip = (i == HH-1) ? HH-2 : i + 1;
    const _Float16* fb  = f + (size_t)b * (HH*ROW);
    const _Float16* frm = fb + (size_t)im * ROW;
    const _Float16* fr0 = fb + (size_t)i  * ROW;
    const _Float16* frp = fb + (size_t)ip * ROW;

    const int lane = t & 63;
    const int srcm = (lane & 48) | ((lane - 1) & 15);   // c-group lane-1 (cyclic)
    const int srcp = (lane & 48) | ((lane + 1) & 15);   // c-group lane+1 (cyclic)
    const int w0 = t >> 4, c0 = (t & 15) << 2;
    const int qch[2] = { t*4, t*4 + 4096 };
    const int wch[2] = { w0, w0 + 64 };

    // ---- phase 1: S <- y2 rows i-1,i,i+1 (DMA, zero-pad OOB);
    //               B0 <- f[im], B1 <- f[ip] (fp32); prefetch f[i].
    if (t < 192) {                                  // zero S edge slots 0/129
        int rr = t >> 6, s = (t >> 5) & 1;
        *(float*)(S + rr*ROWB + (s ? 129*SLOTB : 0) + ((t & 31) << 2)) = 0.f;
    }
    {
        const _Float16* yb = y2 + (size_t)b * (HH*ROW);
        #pragma unroll
        for (int r = 0; r < 3; ++r) {
            int iy = i - 1 + r;                     // TRUE row (zero-pad conv)
            char* lb = S + r*ROWB + SLOTB;          // interior slots 1..128
            if (iy >= 0 && iy < HH) {
                const _Float16* gp = yb + (size_t)iy*ROW + t*8;
                __builtin_amdgcn_global_load_lds(
                    (const __attribute__((address_space(1))) void*)gp,
                    (__attribute__((address_space(3))) void*)(lb + t*16),
                    16, 0, 0);
            } else {
                half8 z = {};
                *(half8*)(lb + t*16) = z;
            }
        }
    }
    half4v v0a = *(const half4v*)(fr0 + qch[0]);    // prefetch f[i]
    half4v v0b = *(const half4v*)(fr0 + qch[1]);
    #pragma unroll
    for (int k = 0; k < 2; ++k) {
        half4v vm = *(const half4v*)(frm + qch[k]);
        half4v vp = *(const half4v*)(frp + qch[k]);
        floatx4 a = { (float)vm[0], (float)vm[1], (float)vm[2], (float)vm[3] };
        floatx4 p = { (float)vp[0], (float)vp[1], (float)vp[2], (float)vp[3] };
        *(floatx4*)(B0 + qch[k]) = a;
        *(floatx4*)(B1 + qch[k]) = p;
    }
    __syncthreads();                                // drains DMA vmcnt + lgkm

    // ---- phase 2a: Sobel partials from rows i+-1 (REFLECT in W)
    floatx4 Bx4[2], dxp4[2];
    #pragma unroll
    for (int k = 0; k < 2; ++k) {
        int w = wch[k];
        int wm = (w == 0)    ? 1      : w - 1;
        int wp = (w == WW-1) ? WW - 2 : w + 1;
        floatx4 am = *(const floatx4*)(B0 + wm*CC + c0);
        floatx4 a0 = *(const floatx4*)(B0 + w *CC + c0);
        floatx4 ap = *(const floatx4*)(B0 + wp*CC + c0);
        floatx4 bm = *(const floatx4*)(B1 + wm*CC + c0);
        floatx4 b0 = *(const floatx4*)(B1 + w *CC + c0);
        floatx4 bp = *(const floatx4*)(B1 + wp*CC + c0);
        floatx4 dy = (bm + 2.f*b0 + bp) - (am + 2.f*a0 + ap);
        Bx4[k]  = 0.2f * rcp4(dy*dy*0.25f + 1.f);   // Dx*DT
        dxp4[k] = (ap - am) + (bp - bm);
    }

    // ---- phase 2b: conv2 MFMA from S. 16 waves = 8 px-windows x 2 cout-halves
    const int wv = t >> 6;
    const int lm = lane & 15, quad = lane >> 4;
    const int px0 = (wv & 7) << 4, chh = wv >> 3;
    floatx4 ga0 = {0.f,0.f,0.f,0.f}, ga1 = {0.f,0.f,0.f,0.f};
    #pragma unroll
    for (int tap = 0; tap < 9; ++tap) {
        const int di = tap / 3, dj = tap % 3;
        const int slot = px0 + lm + dj;
        const int key  = (slot & 7) << 4;
        const char* abase = S + di*ROWB + slot*SLOTB;
        #pragma unroll
        for (int kc = 0; kc < 2; ++kc) {
            const char* ab = abase + ((kc*64 + quad*16) ^ key);
            half8 a0 = *(const half8*)(ab);
            const _Float16* wb = W2g + (((tap*2 + kc)*4 + quad) << 9)
                               + (chh << 8) + (lm << 3);
            half8 b0 = *(const half8*)(wb);
            half8 b1 = *(const half8*)(wb + 128);
            ga0 = __builtin_amdgcn_mfma_f32_16x16x32_f16(a0, b0, ga0, 0,0,0);
            ga1 = __builtin_amdgcn_mfma_f32_16x16x32_f16(a0, b1, ga1, 0,0,0);
        }
    }
    __syncthreads();                                // B0/B1 reads done

    // ---- phase 3: B0 <- f[i] (regs); B1 <- g (acc restage, [w][64] layout)
    {
        floatx4 f0 = { (float)v0a[0], (float)v0a[1], (float)v0a[2], (float)v0a[3] };
        floatx4 f1 = { (float)v0b[0], (float)v0b[1], (float)v0b[2], (float)v0b[3] };
        *(floatx4*)(B0 + qch[0]) = f0;
        *(floatx4*)(B0 + qch[1]) = f1;
    }
    {
        int cbase = chh*32 + lm;
        #pragma unroll
        for (int nt = 0; nt < 2; ++nt) {
            floatx4 v = nt ? ga1 : ga0;
            int c = cbase + nt*16;
            #pragma unroll
            for (int rv = 0; rv < 4; ++rv)
                B1[(px0 + quad*4 + rv)*CC + c] = v[rv];
        }
    }
    __syncthreads();

    // ---- phase 4: coefficients (proven edge-folded form) + g store to out1
    float* gop = gout + (size_t)rowb * ROW;
    floatx4 cR4[2], cL4[2], cU4[2], cH0[2], cEE[2], cF[2], h4[2], h04[2];
    #pragma unroll
    for (int k = 0; k < 2; ++k) {
        int w = wch[k];
        int wm = (w == 0)    ? 1      : w - 1;      // reflect (sobel dx)
        int wp = (w == WW-1) ? WW - 2 : w + 1;
        int wl = (w + WW - 1) & (WW - 1);           // cyclic (rolls)
        int wr = (w + 1) & (WW - 1);
        floatx4 fm = *(const floatx4*)(B0 + wm*CC + c0);
        floatx4 fv = *(const floatx4*)(B0 + w *CC + c0);
        floatx4 fp = *(const floatx4*)(B0 + wp*CC + c0);
        floatx4 dx = dxp4[k] + 2.f*(fp - fm);
        floatx4 By = 0.2f * rcp4(dx*dx*0.25f + 1.f);     // Dy*DT
        floatx4 Bx = Bx4[k];
        floatx4 gv = *(const floatx4*)(B1 + w *CC + c0);
        floatx4 gl = *(const floatx4*)(B1 + wl*CC + c0);
        floatx4 gr = *(const floatx4*)(B1 + wr*CC + c0);
        *(floatx4*)(gop + qch[k]) = gv;             // g output (== B1 @ qch[k])
        float gdm = __shfl(gv[3], srcm, 64);
        float gup = __shfl(gv[0], srcp, 64);
        floatx4 gd = { gdm, gv[0], gv[1], gv[2] };
        floatx4 gu = { gv[1], gv[2], gv[3], gup };
        floatx4 E  = ((gl - gr) + (gd - gu)) * 0.1f;     // (ux+vy)*DT
        floatx4 Dd = rcp4(1.f + 2.f*Bx + 2.f*By);
        floatx4 P  = 2.f * Bx * Dd;
        floatx4 R  = 2.f * By * Dd;
        floatx4 Q  = (gv * 0.2f) * Dd;              // g*DT*Dd
        cR4[k] = P + Q;
        cL4[k] = P - Q;
        cU4[k] = R + Q;
        cH0[k] = 2.f*Dd - 1.f;             // == Dd*(1-2Bx-2By)
        cEE[k] = -2.f * E * Dd;
        cF[k]  = 0.4f * Dd * fv;           // Dd * 2*DT*f
        h4[k] = fv; h04[k] = fv;
    }
    __syncthreads();                       // B1 reads done before loop writes

    int oWl[2], oWr[2];
    #pragma unroll
    for (int k = 0; k < 2; ++k) {
        int w = wch[k];
        oWl[k] = ((w + WW - 1) & (WW - 1))*CC + c0;
        oWr[k] = ((w + 1) & (WW - 1))*CC + c0;
    }

    // ---- phase 5: K=5 diffusion, ping-pong B0 -> B1 -> ... (last iter reg-only)
    float* cur = B0;
    float* oth = B1;
    for (int it = 0; it < 5; ++it) {
        #pragma unroll
        for (int k = 0; k < 2; ++k) {
            floatx4 hl = *(const floatx4*)(cur + oWl[k]);
            floatx4 hr = *(const floatx4*)(cur + oWr[k]);
            floatx4 hv = h4[k];
            float hdm = __shfl(hv[3], srcm, 64);
            float hup = __shfl(hv[0], srcp, 64);
            floatx4 hd = { hdm, hv[0], hv[1], hv[2] };
            floatx4 hu = { hv[1], hv[2], hv[3], hup };
            floatx4 cD = (cU4[k] - cR4[k]) + cL4[k];     // R - Q
            floatx4 hn = cH0[k]*h04[k] + cEE[k]*hv
                       + cR4[k]*hr + cL4[k]*hl
                       + cU4[k]*hu + cD*hd + cF[k];
            if (it < 4)
                *(floatx4*)(oth + qch[k]) = hn;
            h04[k] = hv; h4[k] = hn;
        }
        if (it < 4) {
            __syncthreads();
            float* tmp = cur; cur = oth; oth = tmp;
        }
    }

    // ---- epilogue: relu(bn_o(h)) from registers, float4 stores
    floatx4 gg = *(const floatx4*)(bog + c0);
    floatx4 vv = *(const floatx4*)(bov + c0);
    floatx4 bb = *(const floatx4*)(bob + c0);
    floatx4 mm = *(const floatx4*)(bom + c0);
    floatx4 s4, bi4;
    #pragma unroll
    for (int j = 0; j < 4; ++j) s4[j] = gg[j] * rsqrtf(vv[j] + 1e-3f);
    bi4 = bb - mm*s4;
    float* op = out + (size_t)rowb * ROW;
    #pragma unroll
    for (int k = 0; k < 2; ++k) {
        floatx4 rr = h4[k]*s4 + bi4;
        #pragma unroll
        for (int j = 0; j < 4; ++j) rr[j] = fmaxf(0.f, rr[j]);
        *(floatx4*)(op + qch[k]) = rr;
    }
}

// ---------------------------------------------------------------------------
extern "C" void kernel_launch(void* const* d_in, const int* in_sizes, int n_in,
                              void* d_out, int out_size, void* d_ws, size_t ws_size,
                              hipStream_t stream)
{
    const float* x    = (const float*)d_in[0];
    const float* f_w  = (const float*)d_in[1];
    const float* g_w  = (const float*)d_in[2];
    const float* bnf_g = (const float*)d_in[3];
    const float* bnf_b = (const float*)d_in[4];
    const float* bnf_m = (const float*)d_in[5];
    const float* bnf_v = (const float*)d_in[6];
    const float* bng_g = (const float*)d_in[7];
    const float* bng_b = (const float*)d_in[8];
    const float* bng_m = (const float*)d_in[9];
    const float* bng_v = (const float*)d_in[10];
    const float* bno_g = (const float*)d_in[11];
    const float* bno_b = (const float*)d_in[12];
    const float* bno_m = (const float*)d_in[13];
    const float* bno_v = (const float*)d_in[14];

    float* out = (float*)d_out;
    const size_t N = (size_t)16 * HH * WW * CC;   // 16,777,216
    _Float16* y2   = (_Float16*)d_ws;             // N halfs (32 MB), PRE-SWIZZLED
    _Float16* fbuf = y2 + N;                      // N halfs
    _Float16* W2f  = y2 + 2*N;                    // 36864 halfs
    _Float16* W2g  = W2f + 36864;

    repack_w<<<288, 256, 0, stream>>>(f_w, g_w, W2f, W2g);
    // conv1: stage relu(bn_f(x)) inline; write f16 f + fused y2=relu(bn_g(f))
    conv_mfma<1,1><<<1024, 256, 0, stream>>>(x, W2f, fbuf, nullptr, y2,
                                             bnf_g, bnf_b, bnf_m, bnf_v,
                                             bng_g, bng_b, bng_m, bng_v);
    // fused conv2 + diffusion + bn_o: g -> out slot 1, h -> out slot 0
    diffuse_fused<<<2048, 1024, 0, stream>>>(fbuf, y2, W2g, out + N, out,
                                             bno_g, bno_b, bno_m, bno_v);
}

// Round 10
// 335.790 us; speedup vs baseline: 1.0017x; 1.0017x over previous
//
#include <hip/hip_runtime.h>

#define HH 128
#define WW 128
#define CC 64
#define ROW (WW*CC)          // 8192 elements per (b,h) row
#define SLOTB 128            // bytes per px slot in conv LDS (64 f16, linear)
#define ROWB (130*SLOTB)     // 16640 B per staged row (130 slots)
#define FSTR 68              // conv epilogue restage stride (floats) - conflict-free

typedef _Float16 half8 __attribute__((ext_vector_type(8)));
typedef _Float16 half4v __attribute__((ext_vector_type(4)));
typedef float floatx4 __attribute__((ext_vector_type(4)));

__device__ inline floatx4 rcp4(floatx4 v)
{
    floatx4 r;
    r[0] = __builtin_amdgcn_rcpf(v[0]);
    r[1] = __builtin_amdgcn_rcpf(v[1]);
    r[2] = __builtin_amdgcn_rcpf(v[2]);
    r[3] = __builtin_amdgcn_rcpf(v[3]);
    return r;
}

// ---------------------------------------------------------------------------
// Repack HWIO fp32 weights [3][3][64][64] -> f16 B-frag layout:
// W2[(step*4+q)*512 + o*8 + j] = W[tap][kc*32+q*8+j][o], step = tap*2+kc
// ---------------------------------------------------------------------------
__global__ __launch_bounds__(256)
void repack_w(const float* __restrict__ wf, const float* __restrict__ wg,
              _Float16* __restrict__ W2f, _Float16* __restrict__ W2g)
{
    int idx = blockIdx.x * 256 + threadIdx.x;      // 0..73727
    int sel = idx >= 36864;
    int id  = sel ? idx - 36864 : idx;             // (t*64 + c)*64 + o
    const float* src = sel ? wg : wf;
    _Float16* dst = sel ? W2g : W2f;
    int t = id >> 12, c = (id >> 6) & 63, o = id & 63;
    int kc = c >> 5, q = (c >> 3) & 3, j = c & 7;
    int pos = ((((t*2 + kc)*4 + q)*64 + o) << 3) + j;
    dst[pos] = (_Float16)src[id];
}

// ---------------------------------------------------------------------------
// conv1: implicit-GEMM 3x3 SAME conv via f16 MFMA. EXACT R9 form (the best-
// measured 321us config): 256 thr, 2-row blocks, 2 blocks/CU, acc[4][4].
// Writes f16 fbuf + PRE-SWIZZLED y2 = relu(bn_g(acc)) for the fused kernel's
// global_load_lds staging. XOR channel-block swizzle, FSTR=68 restage.
// ---------------------------------------------------------------------------
template<int BNIN, int EPI>
__global__ __launch_bounds__(256, 2)
void conv_mfma(const void* __restrict__ srcv, const _Float16* __restrict__ W2,
               _Float16* __restrict__ outH, float* __restrict__ outF,
               _Float16* __restrict__ y2,
               const float* __restrict__ ig, const float* __restrict__ ib,
               const float* __restrict__ imu, const float* __restrict__ iva,
               const float* __restrict__ og, const float* __restrict__ ob,
               const float* __restrict__ om, const float* __restrict__ ov)
{
    __shared__ __align__(16) char smem[69632];     // max(stage 66560, restage 69632)
    const int t = threadIdx.x;
    const int blk = ((blockIdx.x & 7) << 7) | (blockIdx.x >> 3);  // XCD swizzle
    const int b = blk >> 6, i0 = (blk & 63) * 2;

    const int c8 = (t & 7) << 3;
    float scv[8], biv[8];
    if (BNIN) {
        #pragma unroll
        for (int j = 0; j < 8; ++j) {
            float s = ig[c8+j] * rsqrtf(iva[c8+j] + 1e-3f);
            scv[j] = s; biv[j] = ib[c8+j] - imu[c8+j]*s;
        }
    }

    // zero edge pixel slots (0 and 129) x 4 rows
    {
        int rr = t >> 6, s = (t >> 5) & 1;
        *(float*)(smem + rr*ROWB + (s ? 129*SLOTB : 0) + ((t & 31) << 2)) = 0.f;
    }

    // ---- stage 4 input rows (i0-1 .. i0+2)
    if (BNIN) {
        for (int r = 0; r < 4; ++r) {
            int iy = i0 - 1 + r;
            bool inb = (iy >= 0) && (iy < HH);
            #pragma unroll
            for (int k = 0; k < 4; ++k) {
                int idx = t + (k << 8);
                int px = idx >> 3;
                half8 v = {0,0,0,0,0,0,0,0};
                if (inb) {
                    const float* gp = (const float*)srcv
                        + ((size_t)(b*HH + iy))*ROW + px*CC + c8;
                    float4 u0 = *(const float4*)gp;
                    float4 u1 = *(const float4*)(gp + 4);
                    v[0] = (_Float16)fmaxf(0.f, u0.x*scv[0] + biv[0]);
                    v[1] = (_Float16)fmaxf(0.f, u0.y*scv[1] + biv[1]);
                    v[2] = (_Float16)fmaxf(0.f, u0.z*scv[2] + biv[2]);
                    v[3] = (_Float16)fmaxf(0.f, u0.w*scv[3] + biv[3]);
                    v[4] = (_Float16)fmaxf(0.f, u1.x*scv[4] + biv[4]);
                    v[5] = (_Float16)fmaxf(0.f, u1.y*scv[5] + biv[5]);
                    v[6] = (_Float16)fmaxf(0.f, u1.z*scv[6] + biv[6]);
                    v[7] = (_Float16)fmaxf(0.f, u1.w*scv[7] + biv[7]);
                }
                int key = ((px + 1) & 7) << 4;
                *(half8*)(smem + r*ROWB + (px + 1)*SLOTB
                          + ((((t & 7) << 4)) ^ key)) = v;
            }
        }
    } else {
        const _Float16* src = (const _Float16*)srcv;
        #pragma unroll
        for (int r = 0; r < 4; ++r) {
            int iy = i0 - 1 + r;
            char* lb = smem + r*ROWB + SLOTB;
            if (iy >= 0 && iy < HH) {
                const _Float16* gp = src + (size_t)(b*HH + iy)*ROW;
                #pragma unroll
                for (int k = 0; k < 4; ++k) {
                    int eo = ((k << 8) + t) << 3;
                    __builtin_amdgcn_global_load_lds(
                        (const __attribute__((address_space(1))) void*)(gp + eo),
                        (__attribute__((address_space(3))) void*)(lb + (eo << 1)),
                        16, 0, 0);
                }
            } else {
                half8 z = {0,0,0,0,0,0,0,0};
                #pragma unroll
                for (int k = 0; k < 4; ++k)
                    *(half8*)(lb + (((k << 8) + t) << 4)) = z;
            }
        }
    }
    __syncthreads();

    const int wv = t >> 6, lane = t & 63;
    const int lm = lane & 15, quad = lane >> 4;
    const int r  = wv >> 1;
    const int px0 = (wv & 1) * 64;
    floatx4 z4 = {0.f,0.f,0.f,0.f};
    floatx4 acc[4][4];
    #pragma unroll
    for (int ms = 0; ms < 4; ++ms)
        #pragma unroll
        for (int nt = 0; nt < 4; ++nt) acc[ms][nt] = z4;

    #pragma unroll
    for (int tap = 0; tap < 9; ++tap) {
        const int di = tap / 3, dj = tap % 3;
        const int slot = px0 + lm + dj;
        const int key  = (slot & 7) << 4;
        const char* abase = smem + (r + di)*ROWB + slot*SLOTB;
        #pragma unroll
        for (int kc = 0; kc < 2; ++kc) {
            const char* ab = abase + ((kc*64 + quad*16) ^ key);
            half8 a0 = *(const half8*)(ab);
            half8 a1 = *(const half8*)(ab + 16*SLOTB);
            half8 a2 = *(const half8*)(ab + 32*SLOTB);
            half8 a3 = *(const half8*)(ab + 48*SLOTB);
            const _Float16* wb = W2 + (((tap*2 + kc)*4 + quad) << 9) + (lm << 3);
            half8 b0 = *(const half8*)(wb);
            half8 b1 = *(const half8*)(wb + 128);
            half8 b2 = *(const half8*)(wb + 256);
            half8 b3 = *(const half8*)(wb + 384);
            acc[0][0] = __builtin_amdgcn_mfma_f32_16x16x32_f16(a0, b0, acc[0][0], 0,0,0);
            acc[1][0] = __builtin_amdgcn_mfma_f32_16x16x32_f16(a1, b0, acc[1][0], 0,0,0);
            acc[2][0] = __builtin_amdgcn_mfma_f32_16x16x32_f16(a2, b0, acc[2][0], 0,0,0);
            acc[3][0] = __builtin_amdgcn_mfma_f32_16x16x32_f16(a3, b0, acc[3][0], 0,0,0);
            acc[0][1] = __builtin_amdgcn_mfma_f32_16x16x32_f16(a0, b1, acc[0][1], 0,0,0);
            acc[1][1] = __builtin_amdgcn_mfma_f32_16x16x32_f16(a1, b1, acc[1][1], 0,0,0);
            acc[2][1] = __builtin_amdgcn_mfma_f32_16x16x32_f16(a2, b1, acc[2][1], 0,0,0);
            acc[3][1] = __builtin_amdgcn_mfma_f32_16x16x32_f16(a3, b1, acc[3][1], 0,0,0);
            acc[0][2] = __builtin_amdgcn_mfma_f32_16x16x32_f16(a0, b2, acc[0][2], 0,0,0);
            acc[1][2] = __builtin_amdgcn_mfma_f32_16x16x32_f16(a1, b2, acc[1][2], 0,0,0);
            acc[2][2] = __builtin_amdgcn_mfma_f32_16x16x32_f16(a2, b2, acc[2][2], 0,0,0);
            acc[3][2] = __builtin_amdgcn_mfma_f32_16x16x32_f16(a3, b2, acc[3][2], 0,0,0);
            acc[0][3] = __builtin_amdgcn_mfma_f32_16x16x32_f16(a0, b3, acc[0][3], 0,0,0);
            acc[1][3] = __builtin_amdgcn_mfma_f32_16x16x32_f16(a1, b3, acc[1][3], 0,0,0);
            acc[2][3] = __builtin_amdgcn_mfma_f32_16x16x32_f16(a2, b3, acc[2][3], 0,0,0);
            acc[3][3] = __builtin_amdgcn_mfma_f32_16x16x32_f16(a3, b3, acc[3][3], 0,0,0);
        }
    }

    // ---- epilogue: restage fp32 acc -> LDS [256 px][FSTR], vector copy-out
    __syncthreads();
    float* sF = (float*)smem;
    #pragma unroll
    for (int nt = 0; nt < 4; ++nt) {
        int c = nt*16 + lm;
        #pragma unroll
        for (int ms = 0; ms < 4; ++ms) {
            int pix = r*128 + px0 + ms*16 + quad*4;
            floatx4 v = acc[ms][nt];
            #pragma unroll
            for (int rv = 0; rv < 4; ++rv)
                sF[(pix + rv)*FSTR + c] = v[rv];
        }
    }
    __syncthreads();

    const size_t gbase = ((size_t)(b*HH + i0)) * ROW;
    if (EPI) {
        const int c8o = (t & 7) << 3;
        float s8[8], bb8[8];
        #pragma unroll
        for (int j = 0; j < 8; ++j) {
            float ss = og[c8o+j] * rsqrtf(ov[c8o+j] + 1e-3f);
            s8[j] = ss; bb8[j] = ob[c8o+j] - om[c8o+j]*ss;
        }
        #pragma unroll
        for (int jj = 0; jj < 8; ++jj) {
            int chunk = jj*256 + t;
            int px = chunk >> 3;
            const float* sp = sF + px*FSTR + c8o;
            floatx4 u0 = *(const floatx4*)(sp);
            floatx4 u1 = *(const floatx4*)(sp + 4);
            half8 hv, yv;
            #pragma unroll
            for (int j = 0; j < 4; ++j) {
                hv[j]   = (_Float16)u0[j];
                hv[4+j] = (_Float16)u1[j];
                yv[j]   = (_Float16)fmaxf(0.f, u0[j]*s8[j]   + bb8[j]);
                yv[4+j] = (_Float16)fmaxf(0.f, u1[j]*s8[4+j] + bb8[4+j]);
            }
            size_t oe = gbase + (size_t)px*64 + c8o;
            *(half8*)(outH + oe) = hv;
            int pxr = px & 127;
            int key8 = ((pxr + 1) & 7) << 3;
            *(half8*)(y2 + gbase + (size_t)px*64 + (c8o ^ key8)) = yv;
        }
    } else {
        #pragma unroll
        for (int jj = 0; jj < 8; ++jj) {
            int chunk = jj*256 + t;
            int px = chunk >> 3;
            const int cc = (t & 7) << 3;
            const float* sp = sF + px*FSTR + cc;
            size_t oe = gbase + (size_t)px*64 + cc;
            *(floatx4*)(outF + oe)     = *(const floatx4*)(sp);
            *(floatx4*)(outF + oe + 4) = *(const floatx4*)(sp + 4);
        }
    }
}

// ---------------------------------------------------------------------------
// R15 FUSED: conv2 + Sobel + K=5 diffusion + relu(bn_o). One block per (b,h)
// row, 1024 thr, 1 block/CU (LDS 115456 B), 16 waves/CU.
// R15 fix vs R14: __launch_bounds__(1024, 1). R14's (1024,4) pinned VGPR at
// 64 -> ~64 MB scratch-spill writes (WRITE_SIZE 195.9 vs 131 MB legit) and
// VALUBusy 28%. LDS already limits to 1 block/CU = 4 waves/SIMD, so the
// budget is 128 VGPR/wave; min-waves=1 lets the allocator use it.
// ---------------------------------------------------------------------------
__global__ __launch_bounds__(1024, 1)
void diffuse_fused(const _Float16* __restrict__ f, const _Float16* __restrict__ y2,
                   const _Float16* __restrict__ W2g,
                   float* __restrict__ gout, float* __restrict__ out,
                   const float* __restrict__ bog, const float* __restrict__ bob,
                   const float* __restrict__ bom, const float* __restrict__ bov)
{
    __shared__ __align__(16) char S[3*ROWB];       // 49920 B y2 slot-stage
    __shared__ float B0[ROW], B1[ROW];             // 2 x 32 KB
    const int t = threadIdx.x;
    const int rowb = ((blockIdx.x & 7) << 8) | (blockIdx.x >> 3);  // XCD swizzle
    const int b = rowb >> 7, i = rowb & 127;
    const int im = (i == 0)    ? 1    : i - 1;     // reflect (Sobel)
    const int ip = (i == HH-1) ? HH-2 : i + 1;
    const _Float16* fb  = f + (size_t)b * (HH*ROW);
    const _Float16* frm = fb + (size_t)im * ROW;
    const _Float16* fr0 = fb + (size_t)i  * ROW;
    const _Float16* frp = fb + (size_t)ip * ROW;

    const int lane = t & 63;
    const int srcm = (lane & 48) | ((lane - 1) & 15);   // c-group lane-1 (cyclic)
    const int srcp = (lane & 48) | ((lane + 1) & 15);   // c-group lane+1 (cyclic)
    const int w0 = t >> 4, c0 = (t & 15) << 2;
    const int qch[2] = { t*4, t*4 + 4096 };
    const int wch[2] = { w0, w0 + 64 };

    // ---- phase 1: S <- y2 rows i-1,i,i+1 (DMA, zero-pad OOB);
    //               B0 <- f[im], B1 <- f[ip] (fp32); prefetch f[i].
    if (t < 192) {                                  // zero S edge slots 0/129
        int rr = t >> 6, s = (t >> 5) & 1;
        *(float*)(S + rr*ROWB + (s ? 129*SLOTB : 0) + ((t & 31) << 2)) = 0.f;
    }
    {
        const _Float16* yb = y2 + (size_t)b * (HH*ROW);
        #pragma unroll
        for (int r = 0; r < 3; ++r) {
            int iy = i - 1 + r;                     // TRUE row (zero-pad conv)
            char* lb = S + r*ROWB + SLOTB;          // interior slots 1..128
            if (iy >= 0 && iy < HH) {
                const _Float16* gp = yb + (size_t)iy*ROW + t*8;
                __builtin_amdgcn_global_load_lds(
                    (const __attribute__((address_space(1))) void*)gp,
                    (__attribute__((address_space(3))) void*)(lb + t*16),
                    16, 0, 0);
            } else {
                half8 z = {};
                *(half8*)(lb + t*16) = z;
            }
        }
    }
    half4v v0a = *(const half4v*)(fr0 + qch[0]);    // prefetch f[i]
    half4v v0b = *(const half4v*)(fr0 + qch[1]);
    #pragma unroll
    for (int k = 0; k < 2; ++k) {
        half4v vm = *(const half4v*)(frm + qch[k]);
        half4v vp = *(const half4v*)(frp + qch[k]);
        floatx4 a = { (float)vm[0], (float)vm[1], (float)vm[2], (float)vm[3] };
        floatx4 p = { (float)vp[0], (float)vp[1], (float)vp[2], (float)vp[3] };
        *(floatx4*)(B0 + qch[k]) = a;
        *(floatx4*)(B1 + qch[k]) = p;
    }
    __syncthreads();                                // drains DMA vmcnt + lgkm

    // ---- phase 2a: Sobel partials from rows i+-1 (REFLECT in W)
    floatx4 Bx4[2], dxp4[2];
    #pragma unroll
    for (int k = 0; k < 2; ++k) {
        int w = wch[k];
        int wm = (w == 0)    ? 1      : w - 1;
        int wp = (w == WW-1) ? WW - 2 : w + 1;
        floatx4 am = *(const floatx4*)(B0 + wm*CC + c0);
        floatx4 a0 = *(const floatx4*)(B0 + w *CC + c0);
        floatx4 ap = *(const floatx4*)(B0 + wp*CC + c0);
        floatx4 bm = *(const floatx4*)(B1 + wm*CC + c0);
        floatx4 b0 = *(const floatx4*)(B1 + w *CC + c0);
        floatx4 bp = *(const floatx4*)(B1 + wp*CC + c0);
        floatx4 dy = (bm + 2.f*b0 + bp) - (am + 2.f*a0 + ap);
        Bx4[k]  = 0.2f * rcp4(dy*dy*0.25f + 1.f);   // Dx*DT
        dxp4[k] = (ap - am) + (bp - bm);
    }

    // ---- phase 2b: conv2 MFMA from S. 16 waves = 8 px-windows x 2 cout-halves
    const int wv = t >> 6;
    const int lm = lane & 15, quad = lane >> 4;
    const int px0 = (wv & 7) << 4, chh = wv >> 3;
    floatx4 ga0 = {0.f,0.f,0.f,0.f}, ga1 = {0.f,0.f,0.f,0.f};
    #pragma unroll
    for (int tap = 0; tap < 9; ++tap) {
        const int di = tap / 3, dj = tap % 3;
        const int slot = px0 + lm + dj;
        const int key  = (slot & 7) << 4;
        const char* abase = S + di*ROWB + slot*SLOTB;
        #pragma unroll
        for (int kc = 0; kc < 2; ++kc) {
            const char* ab = abase + ((kc*64 + quad*16) ^ key);
            half8 a0 = *(const half8*)(ab);
            const _Float16* wb = W2g + (((tap*2 + kc)*4 + quad) << 9)
                               + (chh << 8) + (lm << 3);
            half8 b0 = *(const half8*)(wb);
            half8 b1 = *(const half8*)(wb + 128);
            ga0 = __builtin_amdgcn_mfma_f32_16x16x32_f16(a0, b0, ga0, 0,0,0);
            ga1 = __builtin_amdgcn_mfma_f32_16x16x32_f16(a0, b1, ga1, 0,0,0);
        }
    }
    __syncthreads();                                // B0/B1 reads done

    // ---- phase 3: B0 <- f[i] (regs); B1 <- g (acc restage, [w][64] layout)
    {
        floatx4 f0 = { (float)v0a[0], (float)v0a[1], (float)v0a[2], (float)v0a[3] };
        floatx4 f1 = { (float)v0b[0], (float)v0b[1], (float)v0b[2], (float)v0b[3] };
        *(floatx4*)(B0 + qch[0]) = f0;
        *(floatx4*)(B0 + qch[1]) = f1;
    }
    {
        int cbase = chh*32 + lm;
        #pragma unroll
        for (int nt = 0; nt < 2; ++nt) {
            floatx4 v = nt ? ga1 : ga0;
            int c = cbase + nt*16;
            #pragma unroll
            for (int rv = 0; rv < 4; ++rv)
                B1[(px0 + quad*4 + rv)*CC + c] = v[rv];
        }
    }
    __syncthreads();

    // ---- phase 4: coefficients (proven edge-folded form) + g store to out1
    float* gop = gout + (size_t)rowb * ROW;
    floatx4 cR4[2], cL4[2], cU4[2], cH0[2], cEE[2], cF[2], h4[2], h04[2];
    #pragma unroll
    for (int k = 0; k < 2; ++k) {
        int w = wch[k];
        int wm = (w == 0)    ? 1      : w - 1;      // reflect (sobel dx)
        int wp = (w == WW-1) ? WW - 2 : w + 1;
        int wl = (w + WW - 1) & (WW - 1);           // cyclic (rolls)
        int wr = (w + 1) & (WW - 1);
        floatx4 fm = *(const floatx4*)(B0 + wm*CC + c0);
        floatx4 fv = *(const floatx4*)(B0 + w *CC + c0);
        floatx4 fp = *(const floatx4*)(B0 + wp*CC + c0);
        floatx4 dx = dxp4[k] + 2.f*(fp - fm);
        floatx4 By = 0.2f * rcp4(dx*dx*0.25f + 1.f);     // Dy*DT
        floatx4 Bx = Bx4[k];
        floatx4 gv = *(const floatx4*)(B1 + w *CC + c0);
        floatx4 gl = *(const floatx4*)(B1 + wl*CC + c0);
        floatx4 gr = *(const floatx4*)(B1 + wr*CC + c0);
        *(floatx4*)(gop + qch[k]) = gv;             // g output (== B1 @ qch[k])
        float gdm = __shfl(gv[3], srcm, 64);
        float gup = __shfl(gv[0], srcp, 64);
        floatx4 gd = { gdm, gv[0], gv[1], gv[2] };
        floatx4 gu = { gv[1], gv[2], gv[3], gup };
        floatx4 E  = ((gl - gr) + (gd - gu)) * 0.1f;     // (ux+vy)*DT
        floatx4 Dd = rcp4(1.f + 2.f*Bx + 2.f*By);
        floatx4 P  = 2.f * Bx * Dd;
        floatx4 R  = 2.f * By * Dd;
        floatx4 Q  = (gv * 0.2f) * Dd;              // g*DT*Dd
        cR4[k] = P + Q;
        cL4[k] = P - Q;
        cU4[k] = R + Q;
        cH0[k] = 2.f*Dd - 1.f;             // == Dd*(1-2Bx-2By)
        cEE[k] = -2.f * E * Dd;
        cF[k]  = 0.4f * Dd * fv;           // Dd * 2*DT*f
        h4[k] = fv; h04[k] = fv;
    }
    __syncthreads();                       // B1 reads done before loop writes

    int oWl[2], oWr[2];
    #pragma unroll
    for (int k = 0; k < 2; ++k) {
        int w = wch[k];
        oWl[k] = ((w + WW - 1) & (WW - 1))*CC + c0;
        oWr[k] = ((w + 1) & (WW - 1))*CC + c0;
    }

    // ---- phase 5: K=5 diffusion, ping-pong B0 -> B1 -> ... (last iter reg-only)
    float* cur = B0;
    float* oth = B1;
    for (int it = 0; it < 5; ++it) {
        #pragma unroll
        for (int k = 0; k < 2; ++k) {
            floatx4 hl = *(const floatx4*)(cur + oWl[k]);
            floatx4 hr = *(const floatx4*)(cur + oWr[k]);
            floatx4 hv = h4[k];
            float hdm = __shfl(hv[3], srcm, 64);
            float hup = __shfl(hv[0], srcp, 64);
            floatx4 hd = { hdm, hv[0], hv[1], hv[2] };
            floatx4 hu = { hv[1], hv[2], hv[3], hup };
            floatx4 cD = (cU4[k] - cR4[k]) + cL4[k];     // R - Q
            floatx4 hn = cH0[k]*h04[k] + cEE[k]*hv
                       + cR4[k]*hr + cL4[k]*hl
                       + cU4[k]*hu + cD*hd + cF[k];
            if (it < 4)
                *(floatx4*)(oth + qch[k]) = hn;
            h04[k] = hv; h4[k] = hn;
        }
        if (it < 4) {
            __syncthreads();
            float* tmp = cur; cur = oth; oth = tmp;
        }
    }

    // ---- epilogue: relu(bn_o(h)) from registers, float4 stores
    floatx4 gg = *(const floatx4*)(bog + c0);
    floatx4 vv = *(const floatx4*)(bov + c0);
    floatx4 bb = *(const floatx4*)(bob + c0);
    floatx4 mm = *(const floatx4*)(bom + c0);
    floatx4 s4, bi4;
    #pragma unroll
    for (int j = 0; j < 4; ++j) s4[j] = gg[j] * rsqrtf(vv[j] + 1e-3f);
    bi4 = bb - mm*s4;
    float* op = out + (size_t)rowb * ROW;
    #pragma unroll
    for (int k = 0; k < 2; ++k) {
        floatx4 rr = h4[k]*s4 + bi4;
        #pragma unroll
        for (int j = 0; j < 4; ++j) rr[j] = fmaxf(0.f, rr[j]);
        *(floatx4*)(op + qch[k]) = rr;
    }
}

// ---------------------------------------------------------------------------
extern "C" void kernel_launch(void* const* d_in, const int* in_sizes, int n_in,
                              void* d_out, int out_size, void* d_ws, size_t ws_size,
                              hipStream_t stream)
{
    const float* x    = (const float*)d_in[0];
    const float* f_w  = (const float*)d_in[1];
    const float* g_w  = (const float*)d_in[2];
    const float* bnf_g = (const float*)d_in[3];
    const float* bnf_b = (const float*)d_in[4];
    const float* bnf_m = (const float*)d_in[5];
    const float* bnf_v = (const float*)d_in[6];
    const float* bng_g = (const float*)d_in[7];
    const float* bng_b = (const float*)d_in[8];
    const float* bng_m = (const float*)d_in[9];
    const float* bng_v = (const float*)d_in[10];
    const float* bno_g = (const float*)d_in[11];
    const float* bno_b = (const float*)d_in[12];
    const float* bno_m = (const float*)d_in[13];
    const float* bno_v = (const float*)d_in[14];

    float* out = (float*)d_out;
    const size_t N = (size_t)16 * HH * WW * CC;   // 16,777,216
    _Float16* y2   = (_Float16*)d_ws;             // N halfs (32 MB), PRE-SWIZZLED
    _Float16* fbuf = y2 + N;                      // N halfs
    _Float16* W2f  = y2 + 2*N;                    // 36864 halfs
    _Float16* W2g  = W2f + 36864;

    repack_w<<<288, 256, 0, stream>>>(f_w, g_w, W2f, W2g);
    // conv1: stage relu(bn_f(x)) inline; write f16 f + fused y2=relu(bn_g(f))
    conv_mfma<1,1><<<1024, 256, 0, stream>>>(x, W2f, fbuf, nullptr, y2,
                                             bnf_g, bnf_b, bnf_m, bnf_v,
                                             bng_g, bng_b, bng_m, bng_v);
    // fused conv2 + diffusion + bn_o: g -> out slot 1, h -> out slot 0
    diffuse_fused<<<2048, 1024, 0, stream>>>(fbuf, y2, W2g, out + N, out,
                                             bno_g, bno_b, bno_m, bno_v);
}

// Round 11
// 335.155 us; speedup vs baseline: 1.0036x; 1.0019x over previous
//
#include <hip/hip_runtime.h>

#define HH 128
#define WW 128
#define CC 64
#define ROW (WW*CC)          // 8192 elements per (b,h) row
#define SLOTB 128            // bytes per px slot in conv LDS (64 f16, linear)
#define ROWB (130*SLOTB)     // 16640 B per staged row (130 slots)
#define FSTR 68              // conv epilogue restage stride (floats) - conflict-free

typedef _Float16 half8 __attribute__((ext_vector_type(8)));
typedef _Float16 half4v __attribute__((ext_vector_type(4)));
typedef float floatx4 __attribute__((ext_vector_type(4)));

__device__ inline floatx4 rcp4(floatx4 v)
{
    floatx4 r;
    r[0] = __builtin_amdgcn_rcpf(v[0]);
    r[1] = __builtin_amdgcn_rcpf(v[1]);
    r[2] = __builtin_amdgcn_rcpf(v[2]);
    r[3] = __builtin_amdgcn_rcpf(v[3]);
    return r;
}

// ---------------------------------------------------------------------------
// Repack HWIO fp32 weights [3][3][64][64] -> f16 B-frag layout:
// W2[(step*4+q)*512 + o*8 + j] = W[tap][kc*32+q*8+j][o], step = tap*2+kc
// ---------------------------------------------------------------------------
__global__ __launch_bounds__(256)
void repack_w(const float* __restrict__ wf, const float* __restrict__ wg,
              _Float16* __restrict__ W2f, _Float16* __restrict__ W2g)
{
    int idx = blockIdx.x * 256 + threadIdx.x;      // 0..73727
    int sel = idx >= 36864;
    int id  = sel ? idx - 36864 : idx;             // (t*64 + c)*64 + o
    const float* src = sel ? wg : wf;
    _Float16* dst = sel ? W2g : W2f;
    int t = id >> 12, c = (id >> 6) & 63, o = id & 63;
    int kc = c >> 5, q = (c >> 3) & 3, j = c & 7;
    int pos = ((((t*2 + kc)*4 + q)*64 + o) << 3) + j;
    dst[pos] = (_Float16)src[id];
}

// ---------------------------------------------------------------------------
// conv1: implicit-GEMM 3x3 SAME conv via f16 MFMA. EXACT R9 form (the best-
// measured 321us config): 256 thr, 2-row blocks, 2 blocks/CU, acc[4][4].
// Writes f16 fbuf + PRE-SWIZZLED y2 = relu(bn_g(acc)) for the fused kernel's
// global_load_lds staging. XOR channel-block swizzle, FSTR=68 restage.
// ---------------------------------------------------------------------------
template<int BNIN, int EPI>
__global__ __launch_bounds__(256, 2)
void conv_mfma(const void* __restrict__ srcv, const _Float16* __restrict__ W2,
               _Float16* __restrict__ outH, float* __restrict__ outF,
               _Float16* __restrict__ y2,
               const float* __restrict__ ig, const float* __restrict__ ib,
               const float* __restrict__ imu, const float* __restrict__ iva,
               const float* __restrict__ og, const float* __restrict__ ob,
               const float* __restrict__ om, const float* __restrict__ ov)
{
    __shared__ __align__(16) char smem[69632];     // max(stage 66560, restage 69632)
    const int t = threadIdx.x;
    const int blk = ((blockIdx.x & 7) << 7) | (blockIdx.x >> 3);  // XCD swizzle
    const int b = blk >> 6, i0 = (blk & 63) * 2;

    const int c8 = (t & 7) << 3;
    float scv[8], biv[8];
    if (BNIN) {
        #pragma unroll
        for (int j = 0; j < 8; ++j) {
            float s = ig[c8+j] * rsqrtf(iva[c8+j] + 1e-3f);
            scv[j] = s; biv[j] = ib[c8+j] - imu[c8+j]*s;
        }
    }

    // zero edge pixel slots (0 and 129) x 4 rows
    {
        int rr = t >> 6, s = (t >> 5) & 1;
        *(float*)(smem + rr*ROWB + (s ? 129*SLOTB : 0) + ((t & 31) << 2)) = 0.f;
    }

    // ---- stage 4 input rows (i0-1 .. i0+2)
    if (BNIN) {
        for (int r = 0; r < 4; ++r) {
            int iy = i0 - 1 + r;
            bool inb = (iy >= 0) && (iy < HH);
            #pragma unroll
            for (int k = 0; k < 4; ++k) {
                int idx = t + (k << 8);
                int px = idx >> 3;
                half8 v = {0,0,0,0,0,0,0,0};
                if (inb) {
                    const float* gp = (const float*)srcv
                        + ((size_t)(b*HH + iy))*ROW + px*CC + c8;
                    float4 u0 = *(const float4*)gp;
                    float4 u1 = *(const float4*)(gp + 4);
                    v[0] = (_Float16)fmaxf(0.f, u0.x*scv[0] + biv[0]);
                    v[1] = (_Float16)fmaxf(0.f, u0.y*scv[1] + biv[1]);
                    v[2] = (_Float16)fmaxf(0.f, u0.z*scv[2] + biv[2]);
                    v[3] = (_Float16)fmaxf(0.f, u0.w*scv[3] + biv[3]);
                    v[4] = (_Float16)fmaxf(0.f, u1.x*scv[4] + biv[4]);
                    v[5] = (_Float16)fmaxf(0.f, u1.y*scv[5] + biv[5]);
                    v[6] = (_Float16)fmaxf(0.f, u1.z*scv[6] + biv[6]);
                    v[7] = (_Float16)fmaxf(0.f, u1.w*scv[7] + biv[7]);
                }
                int key = ((px + 1) & 7) << 4;
                *(half8*)(smem + r*ROWB + (px + 1)*SLOTB
                          + ((((t & 7) << 4)) ^ key)) = v;
            }
        }
    } else {
        const _Float16* src = (const _Float16*)srcv;
        #pragma unroll
        for (int r = 0; r < 4; ++r) {
            int iy = i0 - 1 + r;
            char* lb = smem + r*ROWB + SLOTB;
            if (iy >= 0 && iy < HH) {
                const _Float16* gp = src + (size_t)(b*HH + iy)*ROW;
                #pragma unroll
                for (int k = 0; k < 4; ++k) {
                    int eo = ((k << 8) + t) << 3;
                    __builtin_amdgcn_global_load_lds(
                        (const __attribute__((address_space(1))) void*)(gp + eo),
                        (__attribute__((address_space(3))) void*)(lb + (eo << 1)),
                        16, 0, 0);
                }
            } else {
                half8 z = {0,0,0,0,0,0,0,0};
                #pragma unroll
                for (int k = 0; k < 4; ++k)
                    *(half8*)(lb + (((k << 8) + t) << 4)) = z;
            }
        }
    }
    __syncthreads();

    const int wv = t >> 6, lane = t & 63;
    const int lm = lane & 15, quad = lane >> 4;
    const int r  = wv >> 1;
    const int px0 = (wv & 1) * 64;
    floatx4 z4 = {0.f,0.f,0.f,0.f};
    floatx4 acc[4][4];
    #pragma unroll
    for (int ms = 0; ms < 4; ++ms)
        #pragma unroll
        for (int nt = 0; nt < 4; ++nt) acc[ms][nt] = z4;

    #pragma unroll
    for (int tap = 0; tap < 9; ++tap) {
        const int di = tap / 3, dj = tap % 3;
        const int slot = px0 + lm + dj;
        const int key  = (slot & 7) << 4;
        const char* abase = smem + (r + di)*ROWB + slot*SLOTB;
        #pragma unroll
        for (int kc = 0; kc < 2; ++kc) {
            const char* ab = abase + ((kc*64 + quad*16) ^ key);
            half8 a0 = *(const half8*)(ab);
            half8 a1 = *(const half8*)(ab + 16*SLOTB);
            half8 a2 = *(const half8*)(ab + 32*SLOTB);
            half8 a3 = *(const half8*)(ab + 48*SLOTB);
            const _Float16* wb = W2 + (((tap*2 + kc)*4 + quad) << 9) + (lm << 3);
            half8 b0 = *(const half8*)(wb);
            half8 b1 = *(const half8*)(wb + 128);
            half8 b2 = *(const half8*)(wb + 256);
            half8 b3 = *(const half8*)(wb + 384);
            acc[0][0] = __builtin_amdgcn_mfma_f32_16x16x32_f16(a0, b0, acc[0][0], 0,0,0);
            acc[1][0] = __builtin_amdgcn_mfma_f32_16x16x32_f16(a1, b0, acc[1][0], 0,0,0);
            acc[2][0] = __builtin_amdgcn_mfma_f32_16x16x32_f16(a2, b0, acc[2][0], 0,0,0);
            acc[3][0] = __builtin_amdgcn_mfma_f32_16x16x32_f16(a3, b0, acc[3][0], 0,0,0);
            acc[0][1] = __builtin_amdgcn_mfma_f32_16x16x32_f16(a0, b1, acc[0][1], 0,0,0);
            acc[1][1] = __builtin_amdgcn_mfma_f32_16x16x32_f16(a1, b1, acc[1][1], 0,0,0);
            acc[2][1] = __builtin_amdgcn_mfma_f32_16x16x32_f16(a2, b1, acc[2][1], 0,0,0);
            acc[3][1] = __builtin_amdgcn_mfma_f32_16x16x32_f16(a3, b1, acc[3][1], 0,0,0);
            acc[0][2] = __builtin_amdgcn_mfma_f32_16x16x32_f16(a0, b2, acc[0][2], 0,0,0);
            acc[1][2] = __builtin_amdgcn_mfma_f32_16x16x32_f16(a1, b2, acc[1][2], 0,0,0);
            acc[2][2] = __builtin_amdgcn_mfma_f32_16x16x32_f16(a2, b2, acc[2][2], 0,0,0);
            acc[3][2] = __builtin_amdgcn_mfma_f32_16x16x32_f16(a3, b2, acc[3][2], 0,0,0);
            acc[0][3] = __builtin_amdgcn_mfma_f32_16x16x32_f16(a0, b3, acc[0][3], 0,0,0);
            acc[1][3] = __builtin_amdgcn_mfma_f32_16x16x32_f16(a1, b3, acc[1][3], 0,0,0);
            acc[2][3] = __builtin_amdgcn_mfma_f32_16x16x32_f16(a2, b3, acc[2][3], 0,0,0);
            acc[3][3] = __builtin_amdgcn_mfma_f32_16x16x32_f16(a3, b3, acc[3][3], 0,0,0);
        }
    }

    // ---- epilogue: restage fp32 acc -> LDS [256 px][FSTR], vector copy-out
    __syncthreads();
    float* sF = (float*)smem;
    #pragma unroll
    for (int nt = 0; nt < 4; ++nt) {
        int c = nt*16 + lm;
        #pragma unroll
        for (int ms = 0; ms < 4; ++ms) {
            int pix = r*128 + px0 + ms*16 + quad*4;
            floatx4 v = acc[ms][nt];
            #pragma unroll
            for (int rv = 0; rv < 4; ++rv)
                sF[(pix + rv)*FSTR + c] = v[rv];
        }
    }
    __syncthreads();

    const size_t gbase = ((size_t)(b*HH + i0)) * ROW;
    if (EPI) {
        const int c8o = (t & 7) << 3;
        float s8[8], bb8[8];
        #pragma unroll
        for (int j = 0; j < 8; ++j) {
            float ss = og[c8o+j] * rsqrtf(ov[c8o+j] + 1e-3f);
            s8[j] = ss; bb8[j] = ob[c8o+j] - om[c8o+j]*ss;
        }
        #pragma unroll
        for (int jj = 0; jj < 8; ++jj) {
            int chunk = jj*256 + t;
            int px = chunk >> 3;
            const float* sp = sF + px*FSTR + c8o;
            floatx4 u0 = *(const floatx4*)(sp);
            floatx4 u1 = *(const floatx4*)(sp + 4);
            half8 hv, yv;
            #pragma unroll
            for (int j = 0; j < 4; ++j) {
                hv[j]   = (_Float16)u0[j];
                hv[4+j] = (_Float16)u1[j];
                yv[j]   = (_Float16)fmaxf(0.f, u0[j]*s8[j]   + bb8[j]);
                yv[4+j] = (_Float16)fmaxf(0.f, u1[j]*s8[4+j] + bb8[4+j]);
            }
            size_t oe = gbase + (size_t)px*64 + c8o;
            *(half8*)(outH + oe) = hv;
            int pxr = px & 127;
            int key8 = ((pxr + 1) & 7) << 3;
            *(half8*)(y2 + gbase + (size_t)px*64 + (c8o ^ key8)) = yv;
        }
    } else {
        #pragma unroll
        for (int jj = 0; jj < 8; ++jj) {
            int chunk = jj*256 + t;
            int px = chunk >> 3;
            const int cc = (t & 7) << 3;
            const float* sp = sF + px*FSTR + cc;
            size_t oe = gbase + (size_t)px*64 + cc;
            *(floatx4*)(outF + oe)     = *(const floatx4*)(sp);
            *(floatx4*)(outF + oe + 4) = *(const floatx4*)(sp + 4);
        }
    }
}

// ---------------------------------------------------------------------------
// R16 FUSED: conv2 + Sobel + K=5 diffusion + relu(bn_o). One block per (b,h)
// row, 1024 thr, 1 block/CU (LDS 115456 B), 16 waves/CU.
// R16 fix vs R15: amdgpu_waves_per_eu(4,4). Evidence R7/R14/R15: the
// launch_bounds 2nd arg only RAISES the min-waves floor; the allocator's
// occupancy TARGET stays 8 waves/SIMD -> 512/8 = 64 VGPR -> ~64 MB spills
// (WRITE_SIZE 195.9 vs 131 MB legit). LDS already limits to 1 block/CU =
// 4 waves/SIMD, so capping waves/EU at 4 costs nothing and doubles the
// budget to 128 VGPR -> spill-free.
// ---------------------------------------------------------------------------
__global__ __launch_bounds__(1024)
__attribute__((amdgpu_waves_per_eu(4, 4)))
void diffuse_fused(const _Float16* __restrict__ f, const _Float16* __restrict__ y2,
                   const _Float16* __restrict__ W2g,
                   float* __restrict__ gout, float* __restrict__ out,
                   const float* __restrict__ bog, const float* __restrict__ bob,
                   const float* __restrict__ bom, const float* __restrict__ bov)
{
    __shared__ __align__(16) char S[3*ROWB];       // 49920 B y2 slot-stage
    __shared__ float B0[ROW], B1[ROW];             // 2 x 32 KB
    const int t = threadIdx.x;
    const int rowb = ((blockIdx.x & 7) << 8) | (blockIdx.x >> 3);  // XCD swizzle
    const int b = rowb >> 7, i = rowb & 127;
    const int im = (i == 0)    ? 1    : i - 1;     // reflect (Sobel)
    const int ip = (i == HH-1) ? HH-2 : i + 1;
    const _Float16* fb  = f + (size_t)b * (HH*ROW);
    const _Float16* frm = fb + (size_t)im * ROW;
    const _Float16* fr0 = fb + (size_t)i  * ROW;
    const _Float16* frp = fb + (size_t)ip * ROW;

    const int lane = t & 63;
    const int srcm = (lane & 48) | ((lane - 1) & 15);   // c-group lane-1 (cyclic)
    const int srcp = (lane & 48) | ((lane + 1) & 15);   // c-group lane+1 (cyclic)
    const int w0 = t >> 4, c0 = (t & 15) << 2;
    const int qch[2] = { t*4, t*4 + 4096 };
    const int wch[2] = { w0, w0 + 64 };

    // ---- phase 1: S <- y2 rows i-1,i,i+1 (DMA, zero-pad OOB);
    //               B0 <- f[im], B1 <- f[ip] (fp32); prefetch f[i].
    if (t < 192) {                                  // zero S edge slots 0/129
        int rr = t >> 6, s = (t >> 5) & 1;
        *(float*)(S + rr*ROWB + (s ? 129*SLOTB : 0) + ((t & 31) << 2)) = 0.f;
    }
    {
        const _Float16* yb = y2 + (size_t)b * (HH*ROW);
        #pragma unroll
        for (int r = 0; r < 3; ++r) {
            int iy = i - 1 + r;                     // TRUE row (zero-pad conv)
            char* lb = S + r*ROWB + SLOTB;          // interior slots 1..128
            if (iy >= 0 && iy < HH) {
                const _Float16* gp = yb + (size_t)iy*ROW + t*8;
                __builtin_amdgcn_global_load_lds(
                    (const __attribute__((address_space(1))) void*)gp,
                    (__attribute__((address_space(3))) void*)(lb + t*16),
                    16, 0, 0);
            } else {
                half8 z = {};
                *(half8*)(lb + t*16) = z;
            }
        }
    }
    half4v v0a = *(const half4v*)(fr0 + qch[0]);    // prefetch f[i]
    half4v v0b = *(const half4v*)(fr0 + qch[1]);
    #pragma unroll
    for (int k = 0; k < 2; ++k) {
        half4v vm = *(const half4v*)(frm + qch[k]);
        half4v vp = *(const half4v*)(frp + qch[k]);
        floatx4 a = { (float)vm[0], (float)vm[1], (float)vm[2], (float)vm[3] };
        floatx4 p = { (float)vp[0], (float)vp[1], (float)vp[2], (float)vp[3] };
        *(floatx4*)(B0 + qch[k]) = a;
        *(floatx4*)(B1 + qch[k]) = p;
    }
    __syncthreads();                                // drains DMA vmcnt + lgkm

    // ---- phase 2a: Sobel partials from rows i+-1 (REFLECT in W)
    floatx4 Bx4[2], dxp4[2];
    #pragma unroll
    for (int k = 0; k < 2; ++k) {
        int w = wch[k];
        int wm = (w == 0)    ? 1      : w - 1;
        int wp = (w == WW-1) ? WW - 2 : w + 1;
        floatx4 am = *(const floatx4*)(B0 + wm*CC + c0);
        floatx4 a0 = *(const floatx4*)(B0 + w *CC + c0);
        floatx4 ap = *(const floatx4*)(B0 + wp*CC + c0);
        floatx4 bm = *(const floatx4*)(B1 + wm*CC + c0);
        floatx4 b0 = *(const floatx4*)(B1 + w *CC + c0);
        floatx4 bp = *(const floatx4*)(B1 + wp*CC + c0);
        floatx4 dy = (bm + 2.f*b0 + bp) - (am + 2.f*a0 + ap);
        Bx4[k]  = 0.2f * rcp4(dy*dy*0.25f + 1.f);   // Dx*DT
        dxp4[k] = (ap - am) + (bp - bm);
    }

    // ---- phase 2b: conv2 MFMA from S. 16 waves = 8 px-windows x 2 cout-halves
    const int wv = t >> 6;
    const int lm = lane & 15, quad = lane >> 4;
    const int px0 = (wv & 7) << 4, chh = wv >> 3;
    floatx4 ga0 = {0.f,0.f,0.f,0.f}, ga1 = {0.f,0.f,0.f,0.f};
    #pragma unroll
    for (int tap = 0; tap < 9; ++tap) {
        const int di = tap / 3, dj = tap % 3;
        const int slot = px0 + lm + dj;
        const int key  = (slot & 7) << 4;
        const char* abase = S + di*ROWB + slot*SLOTB;
        #pragma unroll
        for (int kc = 0; kc < 2; ++kc) {
            const char* ab = abase + ((kc*64 + quad*16) ^ key);
            half8 a0 = *(const half8*)(ab);
            const _Float16* wb = W2g + (((tap*2 + kc)*4 + quad) << 9)
                               + (chh << 8) + (lm << 3);
            half8 b0 = *(const half8*)(wb);
            half8 b1 = *(const half8*)(wb + 128);
            ga0 = __builtin_amdgcn_mfma_f32_16x16x32_f16(a0, b0, ga0, 0,0,0);
            ga1 = __builtin_amdgcn_mfma_f32_16x16x32_f16(a0, b1, ga1, 0,0,0);
        }
    }
    __syncthreads();                                // B0/B1 reads done

    // ---- phase 3: B0 <- f[i] (regs); B1 <- g (acc restage, [w][64] layout)
    {
        floatx4 f0 = { (float)v0a[0], (float)v0a[1], (float)v0a[2], (float)v0a[3] };
        floatx4 f1 = { (float)v0b[0], (float)v0b[1], (float)v0b[2], (float)v0b[3] };
        *(floatx4*)(B0 + qch[0]) = f0;
        *(floatx4*)(B0 + qch[1]) = f1;
    }
    {
        int cbase = chh*32 + lm;
        #pragma unroll
        for (int nt = 0; nt < 2; ++nt) {
            floatx4 v = nt ? ga1 : ga0;
            int c = cbase + nt*16;
            #pragma unroll
            for (int rv = 0; rv < 4; ++rv)
                B1[(px0 + quad*4 + rv)*CC + c] = v[rv];
        }
    }
    __syncthreads();

    // ---- phase 4: coefficients (proven edge-folded form) + g store to out1
    float* gop = gout + (size_t)rowb * ROW;
    floatx4 cR4[2], cL4[2], cU4[2], cH0[2], cEE[2], cF[2], h4[2], h04[2];
    #pragma unroll
    for (int k = 0; k < 2; ++k) {
        int w = wch[k];
        int wm = (w == 0)    ? 1      : w - 1;      // reflect (sobel dx)
        int wp = (w == WW-1) ? WW - 2 : w + 1;
        int wl = (w + WW - 1) & (WW - 1);           // cyclic (rolls)
        int wr = (w + 1) & (WW - 1);
        floatx4 fm = *(const floatx4*)(B0 + wm*CC + c0);
        floatx4 fv = *(const floatx4*)(B0 + w *CC + c0);
        floatx4 fp = *(const floatx4*)(B0 + wp*CC + c0);
        floatx4 dx = dxp4[k] + 2.f*(fp - fm);
        floatx4 By = 0.2f * rcp4(dx*dx*0.25f + 1.f);     // Dy*DT
        floatx4 Bx = Bx4[k];
        floatx4 gv = *(const floatx4*)(B1 + w *CC + c0);
        floatx4 gl = *(const floatx4*)(B1 + wl*CC + c0);
        floatx4 gr = *(const floatx4*)(B1 + wr*CC + c0);
        *(floatx4*)(gop + qch[k]) = gv;             // g output (== B1 @ qch[k])
        float gdm = __shfl(gv[3], srcm, 64);
        float gup = __shfl(gv[0], srcp, 64);
        floatx4 gd = { gdm, gv[0], gv[1], gv[2] };
        floatx4 gu = { gv[1], gv[2], gv[3], gup };
        floatx4 E  = ((gl - gr) + (gd - gu)) * 0.1f;     // (ux+vy)*DT
        floatx4 Dd = rcp4(1.f + 2.f*Bx + 2.f*By);
        floatx4 P  = 2.f * Bx * Dd;
        floatx4 R  = 2.f * By * Dd;
        floatx4 Q  = (gv * 0.2f) * Dd;              // g*DT*Dd
        cR4[k] = P + Q;
        cL4[k] = P - Q;
        cU4[k] = R + Q;
        cH0[k] = 2.f*Dd - 1.f;             // == Dd*(1-2Bx-2By)
        cEE[k] = -2.f * E * Dd;
        cF[k]  = 0.4f * Dd * fv;           // Dd * 2*DT*f
        h4[k] = fv; h04[k] = fv;
    }
    __syncthreads();                       // B1 reads done before loop writes

    int oWl[2], oWr[2];
    #pragma unroll
    for (int k = 0; k < 2; ++k) {
        int w = wch[k];
        oWl[k] = ((w + WW - 1) & (WW - 1))*CC + c0;
        oWr[k] = ((w + 1) & (WW - 1))*CC + c0;
    }

    // ---- phase 5: K=5 diffusion, ping-pong B0 -> B1 -> ... (last iter reg-only)
    float* cur = B0;
    float* oth = B1;
    for (int it = 0; it < 5; ++it) {
        #pragma unroll
        for (int k = 0; k < 2; ++k) {
            floatx4 hl = *(const floatx4*)(cur + oWl[k]);
            floatx4 hr = *(const floatx4*)(cur + oWr[k]);
            floatx4 hv = h4[k];
            float hdm = __shfl(hv[3], srcm, 64);
            float hup = __shfl(hv[0], srcp, 64);
            floatx4 hd = { hdm, hv[0], hv[1], hv[2] };
            floatx4 hu = { hv[1], hv[2], hv[3], hup };
            floatx4 cD = (cU4[k] - cR4[k]) + cL4[k];     // R - Q
            floatx4 hn = cH0[k]*h04[k] + cEE[k]*hv
                       + cR4[k]*hr + cL4[k]*hl
                       + cU4[k]*hu + cD*hd + cF[k];
            if (it < 4)
                *(floatx4*)(oth + qch[k]) = hn;
            h04[k] = hv; h4[k] = hn;
        }
        if (it < 4) {
            __syncthreads();
            float* tmp = cur; cur = oth; oth = tmp;
        }
    }

    // ---- epilogue: relu(bn_o(h)) from registers, float4 stores
    floatx4 gg = *(const floatx4*)(bog + c0);
    floatx4 vv = *(const floatx4*)(bov + c0);
    floatx4 bb = *(const floatx4*)(bob + c0);
    floatx4 mm = *(const floatx4*)(bom + c0);
    floatx4 s4, bi4;
    #pragma unroll
    for (int j = 0; j < 4; ++j) s4[j] = gg[j] * rsqrtf(vv[j] + 1e-3f);
    bi4 = bb - mm*s4;
    float* op = out + (size_t)rowb * ROW;
    #pragma unroll
    for (int k = 0; k < 2; ++k) {
        floatx4 rr = h4[k]*s4 + bi4;
        #pragma unroll
        for (int j = 0; j < 4; ++j) rr[j] = fmaxf(0.f, rr[j]);
        *(floatx4*)(op + qch[k]) = rr;
    }
}

// ---------------------------------------------------------------------------
extern "C" void kernel_launch(void* const* d_in, const int* in_sizes, int n_in,
                              void* d_out, int out_size, void* d_ws, size_t ws_size,
                              hipStream_t stream)
{
    const float* x    = (const float*)d_in[0];
    const float* f_w  = (const float*)d_in[1];
    const float* g_w  = (const float*)d_in[2];
    const float* bnf_g = (const float*)d_in[3];
    const float* bnf_b = (const float*)d_in[4];
    const float* bnf_m = (const float*)d_in[5];
    const float* bnf_v = (const float*)d_in[6];
    const float* bng_g = (const float*)d_in[7];
    const float* bng_b = (const float*)d_in[8];
    const float* bng_m = (const float*)d_in[9];
    const float* bng_v = (const float*)d_in[10];
    const float* bno_g = (const float*)d_in[11];
    const float* bno_b = (const float*)d_in[12];
    const float* bno_m = (const float*)d_in[13];
    const float* bno_v = (const float*)d_in[14];

    float* out = (float*)d_out;
    const size_t N = (size_t)16 * HH * WW * CC;   // 16,777,216
    _Float16* y2   = (_Float16*)d_ws;             // N halfs (32 MB), PRE-SWIZZLED
    _Float16* fbuf = y2 + N;                      // N halfs
    _Float16* W2f  = y2 + 2*N;                    // 36864 halfs
    _Float16* W2g  = W2f + 36864;

    repack_w<<<288, 256, 0, stream>>>(f_w, g_w, W2f, W2g);
    // conv1: stage relu(bn_f(x)) inline; write f16 f + fused y2=relu(bn_g(f))
    conv_mfma<1,1><<<1024, 256, 0, stream>>>(x, W2f, fbuf, nullptr, y2,
                                             bnf_g, bnf_b, bnf_m, bnf_v,
                                             bng_g, bng_b, bng_m, bng_v);
    // fused conv2 + diffusion + bn_o: g -> out slot 1, h -> out slot 0
    diffuse_fused<<<2048, 1024, 0, stream>>>(fbuf, y2, W2g, out + N, out,
                                             bno_g, bno_b, bno_m, bno_v);
}

// Round 12
// 322.318 us; speedup vs baseline: 1.0436x; 1.0398x over previous
//
#include <hip/hip_runtime.h>

#define HH 128
#define WW 128
#define CC 64
#define ROW (WW*CC)          // 8192 elements per (b,h) row
#define SLOTB 128            // bytes per px slot in conv LDS (64 f16, linear)
#define ROWB (130*SLOTB)     // 16640 B per staged row (130 slots)
#define FSTR 68              // conv epilogue restage stride (floats) - conflict-free

typedef _Float16 half8 __attribute__((ext_vector_type(8)));
typedef _Float16 half4v __attribute__((ext_vector_type(4)));
typedef float floatx4 __attribute__((ext_vector_type(4)));

__device__ inline floatx4 rcp4(floatx4 v)
{
    floatx4 r;
    r[0] = __builtin_amdgcn_rcpf(v[0]);
    r[1] = __builtin_amdgcn_rcpf(v[1]);
    r[2] = __builtin_amdgcn_rcpf(v[2]);
    r[3] = __builtin_amdgcn_rcpf(v[3]);
    return r;
}

// ---------------------------------------------------------------------------
// Repack HWIO fp32 weights [3][3][64][64] -> f16 B-frag layout:
// W2[(step*4+q)*512 + o*8 + j] = W[tap][kc*32+q*8+j][o], step = tap*2+kc
// ---------------------------------------------------------------------------
__global__ __launch_bounds__(256)
void repack_w(const float* __restrict__ wf, const float* __restrict__ wg,
              _Float16* __restrict__ W2f, _Float16* __restrict__ W2g)
{
    int idx = blockIdx.x * 256 + threadIdx.x;      // 0..73727
    int sel = idx >= 36864;
    int id  = sel ? idx - 36864 : idx;             // (t*64 + c)*64 + o
    const float* src = sel ? wg : wf;
    _Float16* dst = sel ? W2g : W2f;
    int t = id >> 12, c = (id >> 6) & 63, o = id & 63;
    int kc = c >> 5, q = (c >> 3) & 3, j = c & 7;
    int pos = ((((t*2 + kc)*4 + q)*64 + o) << 3) + j;
    dst[pos] = (_Float16)src[id];
}

// ---------------------------------------------------------------------------
// Implicit-GEMM 3x3 SAME conv via f16 MFMA. R9 form — BEST MEASURED (321us).
// Block = 2 output rows, 256 thr, 2 blocks/CU, wave = 64px x 64cout acc[4][4].
// LDS: 4 rows x 130 slots x 64 f16 LINEAR with XOR channel-block swizzle
//   LDS(slot,e) = value(px=slot-1, ch = e^((slot&7)<<3)).
// BNIN=0 (conv2): global_load_lds DMA from PRE-SWIZZLED y2.
// BNIN=1 (conv1): BN+relu+cast staging, XOR applied at ds_write.
// Epilogue: fp32 acc restage at stride FSTR=68 (2 lanes/bank), vector copyout;
// conv1 writes y2 pre-swizzled for conv2's DMA.
// REVERT NOTE (R17): R10 ring/R11 512thr/R12 B-preload/R13 1-row/R14-16
// conv2-fusion all measured neutral-or-worse; 1024-thr kernels are capped at
// 64 VGPR by the toolchain (fusion spills ~64MB). This config stands.
// C/D: col(lane&15)=cout, row(quad*4+reg)=pixel  [proven R3-R16]
// ---------------------------------------------------------------------------
template<int BNIN, int EPI>
__global__ __launch_bounds__(256, 2)
void conv_mfma(const void* __restrict__ srcv, const _Float16* __restrict__ W2,
               _Float16* __restrict__ outH, float* __restrict__ outF,
               _Float16* __restrict__ y2,
               const float* __restrict__ ig, const float* __restrict__ ib,
               const float* __restrict__ imu, const float* __restrict__ iva,
               const float* __restrict__ og, const float* __restrict__ ob,
               const float* __restrict__ om, const float* __restrict__ ov)
{
    __shared__ __align__(16) char smem[69632];     // max(stage 66560, restage 69632)
    const int t = threadIdx.x;
    const int blk = ((blockIdx.x & 7) << 7) | (blockIdx.x >> 3);  // XCD swizzle
    const int b = blk >> 6, i0 = (blk & 63) * 2;

    // per-thread BN constants for staging (c8 = (t&7)*8 is k-invariant)
    const int c8 = (t & 7) << 3;
    float scv[8], biv[8];
    if (BNIN) {
        #pragma unroll
        for (int j = 0; j < 8; ++j) {
            float s = ig[c8+j] * rsqrtf(iva[c8+j] + 1e-3f);
            scv[j] = s; biv[j] = ib[c8+j] - imu[c8+j]*s;
        }
    }

    // zero edge pixel slots (0 and 129) x 4 rows: 256 thr x 4 B
    {
        int rr = t >> 6, s = (t >> 5) & 1;
        *(float*)(smem + rr*ROWB + (s ? 129*SLOTB : 0) + ((t & 31) << 2)) = 0.f;
    }

    // ---- stage 4 input rows (i0-1 .. i0+2)
    if (BNIN) {
        for (int r = 0; r < 4; ++r) {
            int iy = i0 - 1 + r;
            bool inb = (iy >= 0) && (iy < HH);
            #pragma unroll
            for (int k = 0; k < 4; ++k) {
                int idx = t + (k << 8);
                int px = idx >> 3;
                half8 v = {0,0,0,0,0,0,0,0};
                if (inb) {
                    const float* gp = (const float*)srcv
                        + ((size_t)(b*HH + iy))*ROW + px*CC + c8;
                    float4 u0 = *(const float4*)gp;
                    float4 u1 = *(const float4*)(gp + 4);
                    v[0] = (_Float16)fmaxf(0.f, u0.x*scv[0] + biv[0]);
                    v[1] = (_Float16)fmaxf(0.f, u0.y*scv[1] + biv[1]);
                    v[2] = (_Float16)fmaxf(0.f, u0.z*scv[2] + biv[2]);
                    v[3] = (_Float16)fmaxf(0.f, u0.w*scv[3] + biv[3]);
                    v[4] = (_Float16)fmaxf(0.f, u1.x*scv[4] + biv[4]);
                    v[5] = (_Float16)fmaxf(0.f, u1.y*scv[5] + biv[5]);
                    v[6] = (_Float16)fmaxf(0.f, u1.z*scv[6] + biv[6]);
                    v[7] = (_Float16)fmaxf(0.f, u1.w*scv[7] + biv[7]);
                }
                int key = ((px + 1) & 7) << 4;             // byte-granular key
                *(half8*)(smem + r*ROWB + (px + 1)*SLOTB
                          + ((((t & 7) << 4)) ^ key)) = v;
            }
        }
    } else {
        // pure-copy staging from pre-swizzled y2 via global_load_lds (16 B)
        const _Float16* src = (const _Float16*)srcv;
        #pragma unroll
        for (int r = 0; r < 4; ++r) {
            int iy = i0 - 1 + r;
            char* lb = smem + r*ROWB + SLOTB;              // interior slots 1..128
            if (iy >= 0 && iy < HH) {
                const _Float16* gp = src + (size_t)(b*HH + iy)*ROW;
                #pragma unroll
                for (int k = 0; k < 4; ++k) {
                    int eo = ((k << 8) + t) << 3;          // elem offset 0..8184
                    __builtin_amdgcn_global_load_lds(
                        (const __attribute__((address_space(1))) void*)(gp + eo),
                        (__attribute__((address_space(3))) void*)(lb + (eo << 1)),
                        16, 0, 0);
                }
            } else {
                half8 z = {0,0,0,0,0,0,0,0};
                #pragma unroll
                for (int k = 0; k < 4; ++k)
                    *(half8*)(lb + (((k << 8) + t) << 4)) = z;
            }
        }
    }
    __syncthreads();

    const int wv = t >> 6, lane = t & 63;
    const int lm = lane & 15, quad = lane >> 4;
    const int r  = wv >> 1;                        // local output row 0/1
    const int px0 = (wv & 1) * 64;
    floatx4 z4 = {0.f,0.f,0.f,0.f};
    floatx4 acc[4][4];
    #pragma unroll
    for (int ms = 0; ms < 4; ++ms)
        #pragma unroll
        for (int nt = 0; nt < 4; ++nt) acc[ms][nt] = z4;

    #pragma unroll
    for (int tap = 0; tap < 9; ++tap) {
        const int di = tap / 3, dj = tap % 3;
        const int slot = px0 + lm + dj;
        const int key  = (slot & 7) << 4;          // preserved under slot+16
        const char* abase = smem + (r + di)*ROWB + slot*SLOTB;
        #pragma unroll
        for (int kc = 0; kc < 2; ++kc) {
            const char* ab = abase + ((kc*64 + quad*16) ^ key);
            half8 a0 = *(const half8*)(ab);
            half8 a1 = *(const half8*)(ab + 16*SLOTB);
            half8 a2 = *(const half8*)(ab + 32*SLOTB);
            half8 a3 = *(const half8*)(ab + 48*SLOTB);
            const _Float16* wb = W2 + (((tap*2 + kc)*4 + quad) << 9) + (lm << 3);
            half8 b0 = *(const half8*)(wb);
            half8 b1 = *(const half8*)(wb + 128);
            half8 b2 = *(const half8*)(wb + 256);
            half8 b3 = *(const half8*)(wb + 384);
            acc[0][0] = __builtin_amdgcn_mfma_f32_16x16x32_f16(a0, b0, acc[0][0], 0,0,0);
            acc[1][0] = __builtin_amdgcn_mfma_f32_16x16x32_f16(a1, b0, acc[1][0], 0,0,0);
            acc[2][0] = __builtin_amdgcn_mfma_f32_16x16x32_f16(a2, b0, acc[2][0], 0,0,0);
            acc[3][0] = __builtin_amdgcn_mfma_f32_16x16x32_f16(a3, b0, acc[3][0], 0,0,0);
            acc[0][1] = __builtin_amdgcn_mfma_f32_16x16x32_f16(a0, b1, acc[0][1], 0,0,0);
            acc[1][1] = __builtin_amdgcn_mfma_f32_16x16x32_f16(a1, b1, acc[1][1], 0,0,0);
            acc[2][1] = __builtin_amdgcn_mfma_f32_16x16x32_f16(a2, b1, acc[2][1], 0,0,0);
            acc[3][1] = __builtin_amdgcn_mfma_f32_16x16x32_f16(a3, b1, acc[3][1], 0,0,0);
            acc[0][2] = __builtin_amdgcn_mfma_f32_16x16x32_f16(a0, b2, acc[0][2], 0,0,0);
            acc[1][2] = __builtin_amdgcn_mfma_f32_16x16x32_f16(a1, b2, acc[1][2], 0,0,0);
            acc[2][2] = __builtin_amdgcn_mfma_f32_16x16x32_f16(a2, b2, acc[2][2], 0,0,0);
            acc[3][2] = __builtin_amdgcn_mfma_f32_16x16x32_f16(a3, b2, acc[3][2], 0,0,0);
            acc[0][3] = __builtin_amdgcn_mfma_f32_16x16x32_f16(a0, b3, acc[0][3], 0,0,0);
            acc[1][3] = __builtin_amdgcn_mfma_f32_16x16x32_f16(a1, b3, acc[1][3], 0,0,0);
            acc[2][3] = __builtin_amdgcn_mfma_f32_16x16x32_f16(a2, b3, acc[2][3], 0,0,0);
            acc[3][3] = __builtin_amdgcn_mfma_f32_16x16x32_f16(a3, b3, acc[3][3], 0,0,0);
        }
    }

    // ---- epilogue: restage fp32 acc -> LDS [256 px][FSTR], vector copy-out
    __syncthreads();                               // all A-frag reads done
    float* sF = (float*)smem;
    #pragma unroll
    for (int nt = 0; nt < 4; ++nt) {
        int c = nt*16 + lm;
        #pragma unroll
        for (int ms = 0; ms < 4; ++ms) {
            int pix = r*128 + px0 + ms*16 + quad*4;
            floatx4 v = acc[ms][nt];
            #pragma unroll
            for (int rv = 0; rv < 4; ++rv)
                sF[(pix + rv)*FSTR + c] = v[rv];
        }
    }
    __syncthreads();

    const size_t gbase = ((size_t)(b*HH + i0)) * ROW;   // 2 contiguous rows
    if (EPI) {
        const int c8o = (t & 7) << 3;
        float s8[8], bb8[8];
        #pragma unroll
        for (int j = 0; j < 8; ++j) {
            float ss = og[c8o+j] * rsqrtf(ov[c8o+j] + 1e-3f);
            s8[j] = ss; bb8[j] = ob[c8o+j] - om[c8o+j]*ss;
        }
        #pragma unroll
        for (int jj = 0; jj < 8; ++jj) {
            int chunk = jj*256 + t;                // 0..2047
            int px = chunk >> 3;                   // 0..255
            const float* sp = sF + px*FSTR + c8o;
            floatx4 u0 = *(const floatx4*)(sp);
            floatx4 u1 = *(const floatx4*)(sp + 4);
            half8 hv, yv;
            #pragma unroll
            for (int j = 0; j < 4; ++j) {
                hv[j]   = (_Float16)u0[j];
                hv[4+j] = (_Float16)u1[j];
                yv[j]   = (_Float16)fmaxf(0.f, u0[j]*s8[j]   + bb8[j]);
                yv[4+j] = (_Float16)fmaxf(0.f, u1[j]*s8[4+j] + bb8[4+j]);
            }
            size_t oe = gbase + (size_t)px*64 + c8o;
            *(half8*)(outH + oe) = hv;
            // y2 stored PRE-SWIZZLED for conv2's global_load_lds staging
            int pxr = px & 127;                    // pixel within its row
            int key8 = ((pxr + 1) & 7) << 3;
            *(half8*)(y2 + gbase + (size_t)px*64 + (c8o ^ key8)) = yv;
        }
    } else {
        #pragma unroll
        for (int jj = 0; jj < 8; ++jj) {
            int chunk = jj*256 + t;
            int px = chunk >> 3;
            const int cc = (t & 7) << 3;
            const float* sp = sF + px*FSTR + cc;
            size_t oe = gbase + (size_t)px*64 + cc;
            *(floatx4*)(outF + oe)     = *(const floatx4*)(sp);
            *(floatx4*)(outF + oe + 4) = *(const floatx4*)(sp + 4);
        }
    }
}

// ---------------------------------------------------------------------------
// Sobel + K=5 diffusion + relu(bn_o). One block per (b,h) row, 1024 thr.
// R8 structure (proven 68us): R6 memory layout ([w][64], float4/lane, C via
// shfl), edge-folded coefficients (6 FMA + 2 ops/elem), rcp, last-iter
// reg-only. 1024-thr VGPR cap of 64 is adequate for this state set.
// ---------------------------------------------------------------------------
__global__ __launch_bounds__(1024, 2)
void diffuse(const _Float16* __restrict__ f, const float* __restrict__ g,
             float* __restrict__ out,
             const float* __restrict__ bog, const float* __restrict__ bob,
             const float* __restrict__ bom, const float* __restrict__ bov)
{
    __shared__ float B0[ROW], B1[ROW];     // 2 x 32 KB
    const int t = threadIdx.x;
    const int rowb = ((blockIdx.x & 7) << 8) | (blockIdx.x >> 3);  // XCD swizzle
    const int b = rowb >> 7, i = rowb & 127;
    const int im = (i == 0)    ? 1    : i - 1;   // reflect
    const int ip = (i == HH-1) ? HH-2 : i + 1;
    const _Float16* fb  = f + (size_t)b * (HH*ROW);
    const _Float16* frm = fb + (size_t)im * ROW;
    const _Float16* fr0 = fb + (size_t)i  * ROW;
    const _Float16* frp = fb + (size_t)ip * ROW;
    const float* grow = g + (size_t)rowb * ROW;

    const int lane = t & 63;
    const int srcm = (lane & 48) | ((lane - 1) & 15);   // c-group lane-1 (cyclic)
    const int srcp = (lane & 48) | ((lane + 1) & 15);   // c-group lane+1 (cyclic)
    const int w0 = t >> 4, c0 = (t & 15) << 2;
    const int qch[2] = { t*4, t*4 + 4096 };
    const int wch[2] = { w0, w0 + 64 };

    // ---- stage f[i-1]->B0, f[i+1]->B1
    #pragma unroll
    for (int k = 0; k < 2; ++k) {
        half4v vm = *(const half4v*)(frm + qch[k]);
        half4v vp = *(const half4v*)(frp + qch[k]);
        floatx4 a = { (float)vm[0], (float)vm[1], (float)vm[2], (float)vm[3] };
        floatx4 p = { (float)vp[0], (float)vp[1], (float)vp[2], (float)vp[3] };
        *(floatx4*)(B0 + qch[k]) = a;
        *(floatx4*)(B1 + qch[k]) = p;
    }
    __syncthreads();

    // ---- Sobel partials from rows i+-1 (REFLECT in W)
    floatx4 Bx4[2], dxp4[2];
    #pragma unroll
    for (int k = 0; k < 2; ++k) {
        int w = wch[k];
        int wm = (w == 0)    ? 1      : w - 1;
        int wp = (w == WW-1) ? WW - 2 : w + 1;
        floatx4 am = *(const floatx4*)(B0 + wm*CC + c0);
        floatx4 a0 = *(const floatx4*)(B0 + w *CC + c0);
        floatx4 ap = *(const floatx4*)(B0 + wp*CC + c0);
        floatx4 bm = *(const floatx4*)(B1 + wm*CC + c0);
        floatx4 b0 = *(const floatx4*)(B1 + w *CC + c0);
        floatx4 bp = *(const floatx4*)(B1 + wp*CC + c0);
        floatx4 dy = (bm + 2.f*b0 + bp) - (am + 2.f*a0 + ap);
        Bx4[k]  = 0.2f * rcp4(dy*dy*0.25f + 1.f);  // Dx*DT
        dxp4[k] = (ap - am) + (bp - bm);
    }
    __syncthreads();

    // ---- stage f[i]->B0 (= h_0), g->B1
    #pragma unroll
    for (int k = 0; k < 2; ++k) {
        half4v v0 = *(const half4v*)(fr0 + qch[k]);
        floatx4 fv = { (float)v0[0], (float)v0[1], (float)v0[2], (float)v0[3] };
        *(floatx4*)(B0 + qch[k]) = fv;
        *(floatx4*)(B1 + qch[k]) = *(const floatx4*)(grow + qch[k]);
    }
    __syncthreads();

    // ---- coefficients (edge-folded form)
    floatx4 cR4[2], cL4[2], cU4[2], cH0[2], cEE[2], cF[2], h4[2], h04[2];
    #pragma unroll
    for (int k = 0; k < 2; ++k) {
        int w = wch[k];
        int wm = (w == 0)    ? 1      : w - 1;     // reflect (sobel dx)
        int wp = (w == WW-1) ? WW - 2 : w + 1;
        int wl = (w + WW - 1) & (WW - 1);          // cyclic (rolls)
        int wr = (w + 1) & (WW - 1);
        floatx4 fm = *(const floatx4*)(B0 + wm*CC + c0);
        floatx4 fv = *(const floatx4*)(B0 + w *CC + c0);
        floatx4 fp = *(const floatx4*)(B0 + wp*CC + c0);
        floatx4 dx = dxp4[k] + 2.f*(fp - fm);
        floatx4 By = 0.2f * rcp4(dx*dx*0.25f + 1.f);    // Dy*DT
        floatx4 Bx = Bx4[k];
        floatx4 gv = *(const floatx4*)(B1 + w *CC + c0);
        floatx4 gl = *(const floatx4*)(B1 + wl*CC + c0);
        floatx4 gr = *(const floatx4*)(B1 + wr*CC + c0);
        float gdm = __shfl(gv[3], srcm, 64);       // g[c0-1] from lane-1
        float gup = __shfl(gv[0], srcp, 64);       // g[c0+4] from lane+1
        floatx4 gd = { gdm, gv[0], gv[1], gv[2] };
        floatx4 gu = { gv[1], gv[2], gv[3], gup };
        floatx4 E  = ((gl - gr) + (gd - gu)) * 0.1f;     // (ux+vy)*DT
        floatx4 Dd = rcp4(1.f + 2.f*Bx + 2.f*By);
        floatx4 P  = 2.f * Bx * Dd;
        floatx4 R  = 2.f * By * Dd;
        floatx4 Q  = (gv * 0.2f) * Dd;             // g*DT*Dd
        cR4[k] = P + Q;
        cL4[k] = P - Q;
        cU4[k] = R + Q;
        cH0[k] = 2.f*Dd - 1.f;            // == Dd*(1-2Bx-2By)
        cEE[k] = -2.f * E * Dd;
        cF[k]  = 0.4f * Dd * fv;          // Dd * 2*DT*f
        h4[k] = fv; h04[k] = fv;
    }
    __syncthreads();                      // g reads done before loop writes B1

    // loop-invariant LDS offsets (W-direction only; C via shfl)
    int oWl[2], oWr[2];
    #pragma unroll
    for (int k = 0; k < 2; ++k) {
        int w = wch[k];
        oWl[k] = ((w + WW - 1) & (WW - 1))*CC + c0;
        oWr[k] = ((w + 1) & (WW - 1))*CC + c0;
    }

    // ---- K=5 diffusion, h ping-pong B0 -> B1 -> B0 ... (last iter reg-only)
    float* cur = B0;
    float* oth = B1;
    for (int it = 0; it < 5; ++it) {
        #pragma unroll
        for (int k = 0; k < 2; ++k) {
            floatx4 hl = *(const floatx4*)(cur + oWl[k]);
            floatx4 hr = *(const floatx4*)(cur + oWr[k]);
            floatx4 hv = h4[k];
            float hdm = __shfl(hv[3], srcm, 64);
            float hup = __shfl(hv[0], srcp, 64);
            floatx4 hd = { hdm, hv[0], hv[1], hv[2] };
            floatx4 hu = { hv[1], hv[2], hv[3], hup };
            floatx4 cD = (cU4[k] - cR4[k]) + cL4[k];     // R - Q
            floatx4 hn = cH0[k]*h04[k] + cEE[k]*hv
                       + cR4[k]*hr + cL4[k]*hl
                       + cU4[k]*hu + cD*hd + cF[k];
            if (it < 4)
                *(floatx4*)(oth + qch[k]) = hn;
            h04[k] = hv; h4[k] = hn;
        }
        if (it < 4) {
            __syncthreads();
            float* tmp = cur; cur = oth; oth = tmp;
        }
    }

    // ---- epilogue: relu(bn_o(h)) from registers, float4 stores
    floatx4 gg = *(const floatx4*)(bog + c0);
    floatx4 vv = *(const floatx4*)(bov + c0);
    floatx4 bb = *(const floatx4*)(bob + c0);
    floatx4 mm = *(const floatx4*)(bom + c0);
    floatx4 s4, bi4;
    #pragma unroll
    for (int j = 0; j < 4; ++j) s4[j] = gg[j] * rsqrtf(vv[j] + 1e-3f);
    bi4 = bb - mm*s4;
    float* op = out + (size_t)rowb * ROW;
    #pragma unroll
    for (int k = 0; k < 2; ++k) {
        floatx4 rr = h4[k]*s4 + bi4;
        #pragma unroll
        for (int j = 0; j < 4; ++j) rr[j] = fmaxf(0.f, rr[j]);
        *(floatx4*)(op + qch[k]) = rr;
    }
}

// ---------------------------------------------------------------------------
extern "C" void kernel_launch(void* const* d_in, const int* in_sizes, int n_in,
                              void* d_out, int out_size, void* d_ws, size_t ws_size,
                              hipStream_t stream)
{
    const float* x    = (const float*)d_in[0];
    const float* f_w  = (const float*)d_in[1];
    const float* g_w  = (const float*)d_in[2];
    const float* bnf_g = (const float*)d_in[3];
    const float* bnf_b = (const float*)d_in[4];
    const float* bnf_m = (const float*)d_in[5];
    const float* bnf_v = (const float*)d_in[6];
    const float* bng_g = (const float*)d_in[7];
    const float* bng_b = (const float*)d_in[8];
    const float* bng_m = (const float*)d_in[9];
    const float* bng_v = (const float*)d_in[10];
    const float* bno_g = (const float*)d_in[11];
    const float* bno_b = (const float*)d_in[12];
    const float* bno_m = (const float*)d_in[13];
    const float* bno_v = (const float*)d_in[14];

    float* out = (float*)d_out;
    const size_t N = (size_t)16 * HH * WW * CC;   // 16,777,216
    _Float16* y2   = (_Float16*)d_ws;             // N halfs (32 MB), PRE-SWIZZLED
    _Float16* fbuf = y2 + N;                      // N halfs
    _Float16* W2f  = y2 + 2*N;                    // 36864 halfs
    _Float16* W2g  = W2f + 36864;

    repack_w<<<288, 256, 0, stream>>>(f_w, g_w, W2f, W2g);
    // conv1: stage relu(bn_f(x)) inline; write f16 f + fused y2=relu(bn_g(f))
    conv_mfma<1,1><<<1024, 256, 0, stream>>>(x, W2f, fbuf, nullptr, y2,
                                             bnf_g, bnf_b, bnf_m, bnf_v,
                                             bng_g, bng_b, bng_m, bng_v);
    // conv2: global_load_lds staging from swizzled y2; write fp32 g to slot 1
    conv_mfma<0,0><<<1024, 256, 0, stream>>>(y2, W2g, nullptr, out + N, nullptr,
                                             nullptr, nullptr, nullptr, nullptr,
                                             nullptr, nullptr, nullptr, nullptr);
    // diffusion + bn_o + relu -> output slot 0
    diffuse<<<2048, 1024, 0, stream>>>(fbuf, out + N, out, bno_g, bno_b, bno_m, bno_v);
}